// Round 11
// baseline (405.858 us; speedup 1.0000x reference)
//
#include <hip/hip_runtime.h>

#define N_NODES 100000
#define E_EDGES 1600000
#define C 128     // IN_C = H1 = H2
#define OUTC 64
#define ZROW N_NODES   // index of the dedicated all-zero Hb row

// ---- CSR build (two-level counting sort) constants ----
#define NPB 128                                   // nodes per bucket (dest >> 7)
#define NBKT ((N_NODES + NPB - 1) / NPB)          // 782 buckets
#define CB_BLOCKS 64                              // phase A/C blocks
#define CB_THREADS 1024
#define EPB ((E_EDGES + CB_BLOCKS - 1) / CB_BLOCKS)  // 25000 edges/block
#define SCM (NBKT * CB_BLOCKS)                    // 50048 scan elements
#define S1B 1024
#define NSB ((SCM + S1B - 1) / S1B)               // 49

typedef __attribute__((ext_vector_type(8))) short bf16x8;
typedef __attribute__((ext_vector_type(4))) float f32x4;
typedef __attribute__((ext_vector_type(2))) float f32x2;

// rne float->bf16
__device__ inline unsigned short f2bf(float x) {
    unsigned u = __float_as_uint(x);
    unsigned r = u + 0x7fffu + ((u >> 16) & 1u);
    return (unsigned short)(r >> 16);
}

__device__ __forceinline__ void packW_body(const float* __restrict__ W,
                                           uint4* __restrict__ Wp, int gtid) {
    // frag (t,s,lane): B[k = s*32 + (lane>>4)*8 + j][n = t*16 + (lane&15)]
    int L = gtid & 63;
    int ts = gtid >> 6;                          // 0..31
    int t = ts >> 2, s = ts & 3;
    int n = t * 16 + (L & 15);
    int k0 = s * 32 + (L >> 4) * 8;
    unsigned e[8];
    #pragma unroll
    for (int j = 0; j < 8; ++j) e[j] = f2bf(W[(k0 + j) * C + n]);
    uint4 v;
    v.x = e[0] | (e[1] << 16);
    v.y = e[2] | (e[3] << 16);
    v.z = e[4] | (e[5] << 16);
    v.w = e[6] | (e[7] << 16);
    Wp[gtid] = v;
}

// exclusive scan of bsum[NSB] computed by the first wave into sbp[] (LDS)
__device__ __forceinline__ void bsum_scan_wave(const int* __restrict__ bsum,
                                               int* __restrict__ sbp, int t) {
    if (t < 64) {
        int v = (t < NSB) ? bsum[t] : 0;
        int x = v;
        #pragma unroll
        for (int o = 1; o < 64; o <<= 1) {
            int y = __shfl_up(x, o);
            if (t >= o) x += y;
        }
        sbp[t] = x - v;                          // exclusive prefix
    }
}

// ---------------- Phase A: histogram + weight packs + ZROW (all independent) ----------------
__global__ __launch_bounds__(CB_THREADS) void k_histpack(const float* __restrict__ W1,
                                                         uint4* __restrict__ Wp1,
                                                         const float* __restrict__ W2,
                                                         uint4* __restrict__ Wp2,
                                                         uint4* __restrict__ Hbz,
                                                         const int* __restrict__ coli,
                                                         int* __restrict__ histG) {
    __shared__ int h[NBKT];
    const int b = blockIdx.x;
    const int t = threadIdx.x;
    // side work on the first 5 blocks (no cross-block dependency)
    if (b < 2)       packW_body(W1, Wp1, b * 1024 + t);
    else if (b < 4)  packW_body(W2, Wp2, (b - 2) * 1024 + t);
    else if (b == 4 && t < 16)
        Hbz[(size_t)ZROW * 16 + t] = make_uint4(0u, 0u, 0u, 0u);

    for (int i = t; i < NBKT; i += CB_THREADS) h[i] = 0;
    __syncthreads();
    const int e0 = b * EPB;
    const int e1 = min(e0 + EPB, E_EDGES);
    for (int e = e0 + t; e < e1; e += CB_THREADS)
        atomicAdd(&h[coli[e] >> 7], 1);
    __syncthreads();
    for (int i = t; i < NBKT; i += CB_THREADS)
        histG[i * CB_BLOCKS + b] = h[i];             // bucket-major
}

// ---------------- Phase B: per-scan-block exclusive scan (base stays block-local) ----------------
__global__ __launch_bounds__(S1B) void k_scanA(const int* __restrict__ in,
                                               int* __restrict__ base,
                                               int* __restrict__ bsum) {
    __shared__ int s[S1B];
    int tid = threadIdx.x;
    int i = blockIdx.x * S1B + tid;
    int v = (i < SCM) ? in[i] : 0;
    s[tid] = v;
    __syncthreads();
    #pragma unroll
    for (int o = 1; o < S1B; o <<= 1) {
        int t = (tid >= o) ? s[tid - o] : 0;
        __syncthreads();
        s[tid] += t;
        __syncthreads();
    }
    if (i < SCM) base[i] = s[tid] - v;               // block-local exclusive
    if (tid == S1B - 1) bsum[blockIdx.x] = s[tid];   // block total
}

// ---------------- Phase C: coarse scatter (global prefix added on the fly) ----------------
__global__ __launch_bounds__(CB_THREADS) void k_coarse(const int* __restrict__ rowi,
                                                       const int* __restrict__ coli,
                                                       const int* __restrict__ base,
                                                       const int* __restrict__ bsum,
                                                       int* __restrict__ tmp) {
    __shared__ int cur[NBKT];
    __shared__ int sbp[64];
    const int b = blockIdx.x;
    const int t = threadIdx.x;
    bsum_scan_wave(bsum, sbp, t);
    __syncthreads();
    for (int i = t; i < NBKT; i += CB_THREADS) {
        int el = i * CB_BLOCKS + b;
        cur[i] = base[el] + sbp[el >> 10];
    }
    __syncthreads();
    const int e0 = b * EPB;
    const int e1 = min(e0 + EPB, E_EDGES);
    for (int e = e0 + t; e < e1; e += CB_THREADS) {
        int c = coli[e];
        int pos = atomicAdd(&cur[c >> 7], 1);
        tmp[pos] = rowi[e] | ((c & 127) << 17);
    }
}

// ---------------- Phase D: fine counting-sort + off[] + dinv[] ----------------
__global__ __launch_bounds__(256) void k_fine(const int* __restrict__ tmp,
                                              const int* __restrict__ base,
                                              const int* __restrict__ bsum,
                                              int* __restrict__ csr,
                                              int* __restrict__ off,
                                              float* __restrict__ dinv) {
    __shared__ int hist[NPB];
    __shared__ int scn[NPB];
    __shared__ int sbp[64];
    const int b = blockIdx.x;
    const int tid = threadIdx.x;
    bsum_scan_wave(bsum, sbp, tid);
    if (tid < NPB) hist[tid] = 0;
    __syncthreads();
    const int el0 = b * CB_BLOCKS;
    const int bb = base[el0] + sbp[el0 >> 10];
    const int be = (b + 1 < NBKT)
                 ? (base[(b + 1) * CB_BLOCKS] + sbp[((b + 1) * CB_BLOCKS) >> 10])
                 : E_EDGES;
    for (int i = bb + tid; i < be; i += 256)
        atomicAdd(&hist[(tmp[i] >> 17) & 127], 1);
    __syncthreads();
    if (tid < NPB) scn[tid] = hist[tid];
    __syncthreads();
    #pragma unroll
    for (int o = 1; o < NPB; o <<= 1) {
        int t = (tid < NPB && tid >= o) ? scn[tid - o] : 0;
        __syncthreads();
        if (tid < NPB) scn[tid] += t;
        __syncthreads();
    }
    if (tid < NPB) {
        int node = b * NPB + tid;
        int excl = scn[tid] - hist[tid];
        if (node < N_NODES) {
            off[node] = bb + excl;
            dinv[node] = rsqrtf((float)(hist[tid] + 1));   // +1 self-loop
        }
        scn[tid] = bb + excl;
    }
    if (b == NBKT - 1 && tid == 0) off[N_NODES] = E_EDGES;
    __syncthreads();
    for (int i = bb + tid; i < be; i += 256) {
        int v = tmp[i];
        int pos = atomicAdd(&scn[(v >> 17) & 127], 1);
        csr[pos] = v & 0x1ffff;
    }
}

// ---------------- MFMA encoder GEMM [N,128]@[128,128] -> bf16, rows scaled by dinv ----------
template <bool BF16IN>
__global__ __launch_bounds__(256) void k_gemm_mfma(const void* __restrict__ Xv,
                                                   const uint4* __restrict__ Wp,
                                                   const float* __restrict__ dinv,
                                                   unsigned short* __restrict__ Hb) {
    __shared__ float xs[64][C];        // 32 KB, reused as bf16 out-staging
    __shared__ float sd[64];
    const int t = threadIdx.x;
    const int r0 = blockIdx.x * 64;
    const bool full = (r0 + 64 <= N_NODES);

    if (BF16IN) {   // stage 64x128 bf16 tile (coalesced uint4)
        const uint4* X4 = (const uint4*)((const unsigned short*)Xv + (size_t)r0 * C);
        uint4* s4 = (uint4*)xs;        // first 16KB
        #pragma unroll
        for (int i = 0; i < 4; ++i) {
            int li = t + i * 256;      // 0..1023, row = li>>4
            if (full || (r0 + (li >> 4) < N_NODES)) s4[li] = X4[li];
            else s4[li] = make_uint4(0u, 0u, 0u, 0u);
        }
    } else {        // stage 64x128 fp32 tile (coalesced float4)
        const float4* X4 = (const float4*)((const float*)Xv + (size_t)r0 * C);
        float4* s4 = (float4*)xs;
        #pragma unroll
        for (int i = 0; i < 8; ++i) {
            int li = t + i * 256;
            if (full || (r0 + (li >> 5) < N_NODES)) s4[li] = X4[li];
            else s4[li] = make_float4(0.f, 0.f, 0.f, 0.f);
        }
    }
    if (t < 64) sd[t] = (r0 + t < N_NODES) ? dinv[r0 + t] : 1.f;
    __syncthreads();

    const int w = t >> 6;              // wave 0..3
    const int lane = t & 63;
    const int m = lane & 15;
    const int q = lane >> 4;
    const int arow = w * 16 + m;       // A row this lane reads

    f32x4 acc[8];
    #pragma unroll
    for (int i = 0; i < 8; ++i) acc[i] = (f32x4){0.f, 0.f, 0.f, 0.f};

    const bf16x8* Wp8 = (const bf16x8*)Wp;
    const unsigned short* xb = (const unsigned short*)xs;
    #pragma unroll
    for (int s = 0; s < 4; ++s) {
        const int k0 = s * 32 + q * 8;
        bf16x8 a;
        if (BF16IN) {
            a = *(const bf16x8*)&xb[arow * C + k0];
        } else {
            float4 va = *(const float4*)&xs[arow][k0];
            float4 vb = *(const float4*)&xs[arow][k0 + 4];
            a[0] = (short)f2bf(va.x); a[1] = (short)f2bf(va.y);
            a[2] = (short)f2bf(va.z); a[3] = (short)f2bf(va.w);
            a[4] = (short)f2bf(vb.x); a[5] = (short)f2bf(vb.y);
            a[6] = (short)f2bf(vb.z); a[7] = (short)f2bf(vb.w);
        }
        #pragma unroll
        for (int tt = 0; tt < 8; ++tt) {
            bf16x8 b = Wp8[(tt * 4 + s) * 64 + lane];
            acc[tt] = __builtin_amdgcn_mfma_f32_16x16x32_bf16(a, b, acc[tt], 0, 0, 0);
        }
    }

    __syncthreads();                   // all waves done reading xs
    unsigned short* hb = (unsigned short*)xs;   // 64x128 bf16 staging
    const int lrb = w * 16 + q * 4;
    #pragma unroll
    for (int r = 0; r < 4; ++r) {
        float sc = sd[lrb + r];
        #pragma unroll
        for (int tt = 0; tt < 8; ++tt)
            hb[(lrb + r) * C + tt * 16 + m] = f2bf(acc[tt][r] * sc);
    }
    __syncthreads();

    // coalesced store: 64x128 bf16 = 1024 uint4
    const uint4* src = (const uint4*)hb;
    uint4* dst = (uint4*)(Hb + (size_t)r0 * C);
    #pragma unroll
    for (int i = 0; i < 4; ++i) {
        int li = t + i * 256;
        if (full || (r0 + (li >> 4) < N_NODES)) dst[li] = src[li];
    }
}

// ---------------- fused aggregation over bf16 scaled rows (+ decode for layer 2) ----------------
// 16 lanes per node (4 nodes per wave). Lane sl owns channels sl*8..sl*8+7.
// RELU=true  (layer 1): out = relu(agg*di + b) -> bf16 [N,128].
// RELU=false (layer 2): emb -> out_emb fp32; then FUSED DECODE with Wd read
//   DIRECTLY from global (32KB, L1/L2-resident, shared by all blocks) — no
//   LDS at all, so occupancy stays at the gather-friendly round-8 level
//   (round 9's 32KB LDS stage cost 65%->38% occupancy = +42us).
#define ACC8(v)                                                             \
    do {                                                                    \
        f32x2 t0 = {__uint_as_float((v).x << 16),                           \
                    __uint_as_float((v).x & 0xffff0000u)};                  \
        f32x2 t1 = {__uint_as_float((v).y << 16),                           \
                    __uint_as_float((v).y & 0xffff0000u)};                  \
        f32x2 t2 = {__uint_as_float((v).z << 16),                           \
                    __uint_as_float((v).z & 0xffff0000u)};                  \
        f32x2 t3 = {__uint_as_float((v).w << 16),                           \
                    __uint_as_float((v).w & 0xffff0000u)};                  \
        acc2[0] += t0;                                                      \
        acc2[1] += t1;                                                      \
        acc2[2] += t2;                                                      \
        acc2[3] += t3;                                                      \
    } while (0)

template <bool RELU>
__global__ __launch_bounds__(256) void k_aggregate(const uint4* __restrict__ Hb4,
                                                   const int* __restrict__ csr,
                                                   const int* __restrict__ off,
                                                   const float* __restrict__ dinv,
                                                   const float* __restrict__ bias,
                                                   void* __restrict__ Aout,
                                                   const float* __restrict__ Wd,
                                                   const float* __restrict__ bd,
                                                   float* __restrict__ out_logp) {
    const int tid = threadIdx.x;
    const int gid = (blockIdx.x * 256 + tid) >> 4;   // node (16 lanes/node); grid exact
    const int sl = tid & 15;                         // 16B chunk of 256B row
    const int grpbase = (tid & 63) & 48;             // group base lane in wave
    const unsigned sl16 = (unsigned)sl << 4;
    const char* Hbb = (const char*)Hb4;
    const int s0 = off[gid];
    const int e1 = off[gid + 1];
    const int deg = e1 - s0;
    const float di = dinv[gid];

    f32x2 acc2[4];
    #pragma unroll
    for (int j = 0; j < 4; ++j) acc2[j] = (f32x2){0.f, 0.f};

    // self row (already dinv[gid]-scaled)
    {
        uint4 v = *(const uint4*)(Hbb + (((unsigned)gid << 8) + sl16));
        ACC8(v);
    }

    // chunk-preload of adjacency indices: lane sl holds csr[s0 + chunk + sl]
    int myidx = csr[min(s0 + sl, E_EDGES - 1)];
    for (int base = 0; base < deg; base += 16) {
        if (base) myidx = csr[min(s0 + base + sl, E_EDGES - 1)];
        for (int q = 0; q < 16 && base + q < deg; q += 4) {
            const int p1 = base + q + 1, p2 = base + q + 2, p3 = base + q + 3;
            int i0 = __shfl(myidx, grpbase + q + 0);           // p0 < deg by loop cond
            int i1 = (p1 < deg) ? __shfl(myidx, grpbase + q + 1) : ZROW;
            int i2 = (p2 < deg) ? __shfl(myidx, grpbase + q + 2) : ZROW;
            int i3 = (p3 < deg) ? __shfl(myidx, grpbase + q + 3) : ZROW;
            uint4 v0 = *(const uint4*)(Hbb + (((unsigned)i0 << 8) + sl16));
            uint4 v1 = *(const uint4*)(Hbb + (((unsigned)i1 << 8) + sl16));
            uint4 v2 = *(const uint4*)(Hbb + (((unsigned)i2 << 8) + sl16));
            uint4 v3 = *(const uint4*)(Hbb + (((unsigned)i3 << 8) + sl16));
            ACC8(v0);
            ACC8(v1);
            ACC8(v2);
            ACC8(v3);
        }
    }

    float4 b0 = ((const float4*)bias)[sl * 2];
    float4 b1 = ((const float4*)bias)[sl * 2 + 1];
    acc2[0] = acc2[0] * di + (f32x2){b0.x, b0.y};
    acc2[1] = acc2[1] * di + (f32x2){b0.z, b0.w};
    acc2[2] = acc2[2] * di + (f32x2){b1.x, b1.y};
    acc2[3] = acc2[3] * di + (f32x2){b1.z, b1.w};

    if (RELU) {
        #pragma unroll
        for (int j = 0; j < 4; ++j) {
            acc2[j].x = fmaxf(acc2[j].x, 0.f);
            acc2[j].y = fmaxf(acc2[j].y, 0.f);
        }
        // pack 8 channels to bf16 and store 16B (row = 256B by 16 lanes)
        uint4 o;
        o.x = (unsigned)f2bf(acc2[0].x) | ((unsigned)f2bf(acc2[0].y) << 16);
        o.y = (unsigned)f2bf(acc2[1].x) | ((unsigned)f2bf(acc2[1].y) << 16);
        o.z = (unsigned)f2bf(acc2[2].x) | ((unsigned)f2bf(acc2[2].y) << 16);
        o.w = (unsigned)f2bf(acc2[3].x) | ((unsigned)f2bf(acc2[3].y) << 16);
        ((uint4*)Aout)[(size_t)gid * 16 + sl] = o;
    } else {
        float ss = 0.f;
        #pragma unroll
        for (int j = 0; j < 4; ++j) ss += acc2[j].x * acc2[j].x + acc2[j].y * acc2[j].y;
        // reduce over the 16 lanes of this group (xor 1,2,4,8 stays in-group)
        #pragma unroll
        for (int o = 1; o < 16; o <<= 1) ss += __shfl_xor(ss, o);
        const float inv = 1.f / (sqrtf(ss) + 1e-12f);

        // normalized embedding, lane-local 8 channels (registers only)
        float hv[8] = {acc2[0].x * inv, acc2[0].y * inv, acc2[1].x * inv, acc2[1].y * inv,
                       acc2[2].x * inv, acc2[2].y * inv, acc2[3].x * inv, acc2[3].y * inv};

        // store embedding (two float4)
        float4* dst = (float4*)((float*)Aout + (size_t)gid * C + sl * 8);
        dst[0] = make_float4(hv[0], hv[1], hv[2], hv[3]);
        dst[1] = make_float4(hv[4], hv[5], hv[6], hv[7]);

        // fused decode: lane computes cols sl*4..sl*4+3 of its node's logits.
        // Wd read straight from global (L1/L2-resident); channel k owned by
        // lane grpbase+(k>>3), elem k&7 — fully unrolled, register-only hv[].
        const float4* WdV = (const float4*)Wd;    // [128][16] float4
        float4 bdv = *(const float4*)&bd[sl * 4];
        float g0 = bdv.x, g1 = bdv.y, g2 = bdv.z, g3 = bdv.w;
        #pragma unroll
        for (int k = 0; k < C; ++k) {
            float hk = __shfl(hv[k & 7], grpbase + (k >> 3));
            float4 w = WdV[k * 16 + sl];
            g0 = fmaf(hk, w.x, g0);
            g1 = fmaf(hk, w.y, g1);
            g2 = fmaf(hk, w.z, g2);
            g3 = fmaf(hk, w.w, g3);
        }
        // log_softmax over the 64 logits of this node (16 lanes x 4 cols)
        float m = fmaxf(fmaxf(g0, g1), fmaxf(g2, g3));
        #pragma unroll
        for (int o = 1; o < 16; o <<= 1) m = fmaxf(m, __shfl_xor(m, o));
        float s = expf(g0 - m) + expf(g1 - m) + expf(g2 - m) + expf(g3 - m);
        #pragma unroll
        for (int o = 1; o < 16; o <<= 1) s += __shfl_xor(s, o);
        float ls = m + logf(s);
        *(float4*)&out_logp[(size_t)gid * OUTC + sl * 4] =
            make_float4(g0 - ls, g1 - ls, g2 - ls, g3 - ls);
    }
}

extern "C" void kernel_launch(void* const* d_in, const int* in_sizes, int n_in,
                              void* d_out, int out_size, void* d_ws, size_t ws_size,
                              hipStream_t stream) {
    const float* x  = (const float*)d_in[0];
    const int*   ei = (const int*)d_in[1];
    const int* rowi = ei;
    const int* coli = ei + E_EDGES;
    const float* W1 = (const float*)d_in[2];
    const float* b1 = (const float*)d_in[3];
    const float* W2 = (const float*)d_in[4];
    const float* b2 = (const float*)d_in[5];
    const float* Wd = (const float*)d_in[6];
    const float* bd = (const float*)d_in[7];

    float* out_logp = (float*)d_out;                             // [N,64]
    float* out_emb  = (float*)d_out + (long long)N_NODES * OUTC; // [N,128]

    // workspace layout (16B-aligned regions)
    char* p = (char*)d_ws;
    float* dinv = (float*)p;                  p += sizeof(float) * N_NODES;
    unsigned short* Hb = (unsigned short*)p;  p += sizeof(short) * (size_t)(N_NODES + 4) * C; // +4 rows (ZROW pad)
    unsigned short* aggb = (unsigned short*)p; p += sizeof(short) * (size_t)N_NODES * C;      // bf16 h1
    int*   off   = (int*)p;                   p += sizeof(int) * (N_NODES + 4);
    int*   histG = (int*)p;                   p += sizeof(int) * SCM;
    int*   base  = (int*)p;                   p += sizeof(int) * SCM;
    int*   bsum  = (int*)p;                   p += sizeof(int) * 64;
    int*   tmp   = (int*)p;                   p += sizeof(int) * (size_t)E_EDGES;
    int*   csr   = (int*)p;                   p += sizeof(int) * (size_t)E_EDGES;
    uint4* Wp1   = (uint4*)p;                 p += sizeof(uint4) * 2048;
    uint4* Wp2   = (uint4*)p;                 p += sizeof(uint4) * 2048;

    // --- CSR front-end: 4 kernels (histogram+packs, scan, coarse, fine) ---
    k_histpack<<<CB_BLOCKS, CB_THREADS, 0, stream>>>(W1, Wp1, W2, Wp2, (uint4*)Hb,
                                                     coli, histG);
    k_scanA<<<NSB, S1B, 0, stream>>>(histG, base, bsum);
    k_coarse<<<CB_BLOCKS, CB_THREADS, 0, stream>>>(rowi, coli, base, bsum, tmp);
    k_fine<<<NBKT, 256, 0, stream>>>(tmp, base, bsum, csr, off, dinv);

    const int GB = (N_NODES + 63) / 64;          // 1563
    const int AB = (N_NODES * 16 + 255) / 256;   // 6250 (16 lanes per node, exact)
    // --- conv1: H1b = (x@W1)*dinv -> gather-agg -> relu -> bf16 aggb ---
    k_gemm_mfma<false><<<GB, 256, 0, stream>>>(x, Wp1, dinv, Hb);
    k_aggregate<true><<<AB, 256, 0, stream>>>((const uint4*)Hb, csr, off, dinv, b1, aggb,
                                              nullptr, nullptr, nullptr);
    // --- conv2: H2b = (aggb@W2)*dinv -> gather-agg -> normalize -> out_emb
    //            + fused decode -> out_logp ---
    k_gemm_mfma<true><<<GB, 256, 0, stream>>>(aggb, Wp2, dinv, Hb);
    k_aggregate<false><<<AB, 256, 0, stream>>>((const uint4*)Hb, csr, off, dinv, b2, out_emb,
                                               Wd, bd, out_logp);
}

// Round 12
// 385.130 us; speedup vs baseline: 1.0538x; 1.0538x over previous
//
#include <hip/hip_runtime.h>

#define N_NODES 100000
#define E_EDGES 1600000
#define C 128     // IN_C = H1 = H2
#define OUTC 64
#define ZROW N_NODES   // index of the dedicated all-zero Hb row

// ---- CSR build (two-level counting sort) constants ----
#define NPB 128                                   // nodes per bucket (dest >> 7)
#define NBKT ((N_NODES + NPB - 1) / NPB)          // 782 buckets
#define CB_BLOCKS 64                              // phase A/C blocks
#define CB_THREADS 1024
#define EPB ((E_EDGES + CB_BLOCKS - 1) / CB_BLOCKS)  // 25000 edges/block
#define SCM (NBKT * CB_BLOCKS)                    // 50048 scan elements
#define S1B 1024
#define NSB ((SCM + S1B - 1) / S1B)               // 49

typedef __attribute__((ext_vector_type(8))) short bf16x8;
typedef __attribute__((ext_vector_type(4))) float f32x4;
typedef __attribute__((ext_vector_type(2))) float f32x2;

// rne float->bf16
__device__ inline unsigned short f2bf(float x) {
    unsigned u = __float_as_uint(x);
    unsigned r = u + 0x7fffu + ((u >> 16) & 1u);
    return (unsigned short)(r >> 16);
}

__device__ __forceinline__ void packW_body(const float* __restrict__ W,
                                           uint4* __restrict__ Wp, int gtid) {
    // frag (t,s,lane): B[k = s*32 + (lane>>4)*8 + j][n = t*16 + (lane&15)]
    int L = gtid & 63;
    int ts = gtid >> 6;                          // 0..31
    int t = ts >> 2, s = ts & 3;
    int n = t * 16 + (L & 15);
    int k0 = s * 32 + (L >> 4) * 8;
    unsigned e[8];
    #pragma unroll
    for (int j = 0; j < 8; ++j) e[j] = f2bf(W[(k0 + j) * C + n]);
    uint4 v;
    v.x = e[0] | (e[1] << 16);
    v.y = e[2] | (e[3] << 16);
    v.z = e[4] | (e[5] << 16);
    v.w = e[6] | (e[7] << 16);
    Wp[gtid] = v;
}

// exclusive scan of bsum[NSB] computed by the first wave into sbp[] (LDS)
__device__ __forceinline__ void bsum_scan_wave(const int* __restrict__ bsum,
                                               int* __restrict__ sbp, int t) {
    if (t < 64) {
        int v = (t < NSB) ? bsum[t] : 0;
        int x = v;
        #pragma unroll
        for (int o = 1; o < 64; o <<= 1) {
            int y = __shfl_up(x, o);
            if (t >= o) x += y;
        }
        sbp[t] = x - v;                          // exclusive prefix
    }
}

// ---------------- Phase A: histogram + weight packs + ZROW (all independent) ----------------
__global__ __launch_bounds__(CB_THREADS) void k_histpack(const float* __restrict__ W1,
                                                         uint4* __restrict__ Wp1,
                                                         const float* __restrict__ W2,
                                                         uint4* __restrict__ Wp2,
                                                         uint4* __restrict__ Hbz,
                                                         const int* __restrict__ coli,
                                                         int* __restrict__ histG) {
    __shared__ int h[NBKT];
    const int b = blockIdx.x;
    const int t = threadIdx.x;
    // side work on the first 5 blocks (no cross-block dependency)
    if (b < 2)       packW_body(W1, Wp1, b * 1024 + t);
    else if (b < 4)  packW_body(W2, Wp2, (b - 2) * 1024 + t);
    else if (b == 4 && t < 16)
        Hbz[(size_t)ZROW * 16 + t] = make_uint4(0u, 0u, 0u, 0u);

    for (int i = t; i < NBKT; i += CB_THREADS) h[i] = 0;
    __syncthreads();
    const int e0 = b * EPB;
    const int e1 = min(e0 + EPB, E_EDGES);
    for (int e = e0 + t; e < e1; e += CB_THREADS)
        atomicAdd(&h[coli[e] >> 7], 1);
    __syncthreads();
    for (int i = t; i < NBKT; i += CB_THREADS)
        histG[i * CB_BLOCKS + b] = h[i];             // bucket-major
}

// ---------------- Phase B: per-scan-block exclusive scan (base stays block-local) ----------------
__global__ __launch_bounds__(S1B) void k_scanA(const int* __restrict__ in,
                                               int* __restrict__ base,
                                               int* __restrict__ bsum) {
    __shared__ int s[S1B];
    int tid = threadIdx.x;
    int i = blockIdx.x * S1B + tid;
    int v = (i < SCM) ? in[i] : 0;
    s[tid] = v;
    __syncthreads();
    #pragma unroll
    for (int o = 1; o < S1B; o <<= 1) {
        int t = (tid >= o) ? s[tid - o] : 0;
        __syncthreads();
        s[tid] += t;
        __syncthreads();
    }
    if (i < SCM) base[i] = s[tid] - v;               // block-local exclusive
    if (tid == S1B - 1) bsum[blockIdx.x] = s[tid];   // block total
}

// ---------------- Phase C: coarse scatter (global prefix added on the fly) ----------------
__global__ __launch_bounds__(CB_THREADS) void k_coarse(const int* __restrict__ rowi,
                                                       const int* __restrict__ coli,
                                                       const int* __restrict__ base,
                                                       const int* __restrict__ bsum,
                                                       int* __restrict__ tmp) {
    __shared__ int cur[NBKT];
    __shared__ int sbp[64];
    const int b = blockIdx.x;
    const int t = threadIdx.x;
    bsum_scan_wave(bsum, sbp, t);
    __syncthreads();
    for (int i = t; i < NBKT; i += CB_THREADS) {
        int el = i * CB_BLOCKS + b;
        cur[i] = base[el] + sbp[el >> 10];
    }
    __syncthreads();
    const int e0 = b * EPB;
    const int e1 = min(e0 + EPB, E_EDGES);
    for (int e = e0 + t; e < e1; e += CB_THREADS) {
        int c = coli[e];
        int pos = atomicAdd(&cur[c >> 7], 1);
        tmp[pos] = rowi[e] | ((c & 127) << 17);
    }
}

// ---------------- Phase D: fine counting-sort + off[] + dinv[] ----------------
__global__ __launch_bounds__(256) void k_fine(const int* __restrict__ tmp,
                                              const int* __restrict__ base,
                                              const int* __restrict__ bsum,
                                              int* __restrict__ csr,
                                              int* __restrict__ off,
                                              float* __restrict__ dinv) {
    __shared__ int hist[NPB];
    __shared__ int scn[NPB];
    __shared__ int sbp[64];
    const int b = blockIdx.x;
    const int tid = threadIdx.x;
    bsum_scan_wave(bsum, sbp, tid);
    if (tid < NPB) hist[tid] = 0;
    __syncthreads();
    const int el0 = b * CB_BLOCKS;
    const int bb = base[el0] + sbp[el0 >> 10];
    const int be = (b + 1 < NBKT)
                 ? (base[(b + 1) * CB_BLOCKS] + sbp[((b + 1) * CB_BLOCKS) >> 10])
                 : E_EDGES;
    for (int i = bb + tid; i < be; i += 256)
        atomicAdd(&hist[(tmp[i] >> 17) & 127], 1);
    __syncthreads();
    if (tid < NPB) scn[tid] = hist[tid];
    __syncthreads();
    #pragma unroll
    for (int o = 1; o < NPB; o <<= 1) {
        int t = (tid < NPB && tid >= o) ? scn[tid - o] : 0;
        __syncthreads();
        if (tid < NPB) scn[tid] += t;
        __syncthreads();
    }
    if (tid < NPB) {
        int node = b * NPB + tid;
        int excl = scn[tid] - hist[tid];
        if (node < N_NODES) {
            off[node] = bb + excl;
            dinv[node] = rsqrtf((float)(hist[tid] + 1));   // +1 self-loop
        }
        scn[tid] = bb + excl;
    }
    if (b == NBKT - 1 && tid == 0) off[N_NODES] = E_EDGES;
    __syncthreads();
    for (int i = bb + tid; i < be; i += 256) {
        int v = tmp[i];
        int pos = atomicAdd(&scn[(v >> 17) & 127], 1);
        csr[pos] = v & 0x1ffff;
    }
}

// ---------------- MFMA encoder GEMM [N,128]@[128,128] -> bf16, rows scaled by dinv ----------
template <bool BF16IN>
__global__ __launch_bounds__(256) void k_gemm_mfma(const void* __restrict__ Xv,
                                                   const uint4* __restrict__ Wp,
                                                   const float* __restrict__ dinv,
                                                   unsigned short* __restrict__ Hb) {
    __shared__ float xs[64][C];        // 32 KB, reused as bf16 out-staging
    __shared__ float sd[64];
    const int t = threadIdx.x;
    const int r0 = blockIdx.x * 64;
    const bool full = (r0 + 64 <= N_NODES);

    if (BF16IN) {   // stage 64x128 bf16 tile (coalesced uint4)
        const uint4* X4 = (const uint4*)((const unsigned short*)Xv + (size_t)r0 * C);
        uint4* s4 = (uint4*)xs;        // first 16KB
        #pragma unroll
        for (int i = 0; i < 4; ++i) {
            int li = t + i * 256;      // 0..1023, row = li>>4
            if (full || (r0 + (li >> 4) < N_NODES)) s4[li] = X4[li];
            else s4[li] = make_uint4(0u, 0u, 0u, 0u);
        }
    } else {        // stage 64x128 fp32 tile (coalesced float4)
        const float4* X4 = (const float4*)((const float*)Xv + (size_t)r0 * C);
        float4* s4 = (float4*)xs;
        #pragma unroll
        for (int i = 0; i < 8; ++i) {
            int li = t + i * 256;
            if (full || (r0 + (li >> 5) < N_NODES)) s4[li] = X4[li];
            else s4[li] = make_float4(0.f, 0.f, 0.f, 0.f);
        }
    }
    if (t < 64) sd[t] = (r0 + t < N_NODES) ? dinv[r0 + t] : 1.f;
    __syncthreads();

    const int w = t >> 6;              // wave 0..3
    const int lane = t & 63;
    const int m = lane & 15;
    const int q = lane >> 4;
    const int arow = w * 16 + m;       // A row this lane reads

    f32x4 acc[8];
    #pragma unroll
    for (int i = 0; i < 8; ++i) acc[i] = (f32x4){0.f, 0.f, 0.f, 0.f};

    const bf16x8* Wp8 = (const bf16x8*)Wp;
    const unsigned short* xb = (const unsigned short*)xs;
    #pragma unroll
    for (int s = 0; s < 4; ++s) {
        const int k0 = s * 32 + q * 8;
        bf16x8 a;
        if (BF16IN) {
            a = *(const bf16x8*)&xb[arow * C + k0];
        } else {
            float4 va = *(const float4*)&xs[arow][k0];
            float4 vb = *(const float4*)&xs[arow][k0 + 4];
            a[0] = (short)f2bf(va.x); a[1] = (short)f2bf(va.y);
            a[2] = (short)f2bf(va.z); a[3] = (short)f2bf(va.w);
            a[4] = (short)f2bf(vb.x); a[5] = (short)f2bf(vb.y);
            a[6] = (short)f2bf(vb.z); a[7] = (short)f2bf(vb.w);
        }
        #pragma unroll
        for (int tt = 0; tt < 8; ++tt) {
            bf16x8 b = Wp8[(tt * 4 + s) * 64 + lane];
            acc[tt] = __builtin_amdgcn_mfma_f32_16x16x32_bf16(a, b, acc[tt], 0, 0, 0);
        }
    }

    __syncthreads();                   // all waves done reading xs
    unsigned short* hb = (unsigned short*)xs;   // 64x128 bf16 staging
    const int lrb = w * 16 + q * 4;
    #pragma unroll
    for (int r = 0; r < 4; ++r) {
        float sc = sd[lrb + r];
        #pragma unroll
        for (int tt = 0; tt < 8; ++tt)
            hb[(lrb + r) * C + tt * 16 + m] = f2bf(acc[tt][r] * sc);
    }
    __syncthreads();

    // coalesced store: 64x128 bf16 = 1024 uint4
    const uint4* src = (const uint4*)hb;
    uint4* dst = (uint4*)(Hb + (size_t)r0 * C);
    #pragma unroll
    for (int i = 0; i < 4; ++i) {
        int li = t + i * 256;
        if (full || (r0 + (li >> 4) < N_NODES)) dst[li] = src[li];
    }
}

// ---------------- fused aggregation over bf16 scaled rows (+ decode for layer 2) ----------------
// 16 lanes per node (BS/16 nodes per block). Lane sl owns channels sl*8..+7.
// RELU=true  (layer 1, BS=256): out = relu(agg*di + b) -> bf16 [N,128].
// RELU=false (layer 2, BS=1024): emb -> out_emb fp32 + fused decode with Wd
//   staged fp32 in 32KB LDS. KEY: at BS=1024 the LDS/wave ratio is 2KB/wave
//   (32KB per 16 waves) so LDS allows 80 waves/CU -> occupancy capped only
//   by the 32-wave HW limit. Round 9's BS=256 (8KB/wave -> 38% occ, 108us)
//   and round 11's global-Wd (L1 thrash, 135us) both lose to this.
#define ACC8(v)                                                             \
    do {                                                                    \
        f32x2 t0 = {__uint_as_float((v).x << 16),                           \
                    __uint_as_float((v).x & 0xffff0000u)};                  \
        f32x2 t1 = {__uint_as_float((v).y << 16),                           \
                    __uint_as_float((v).y & 0xffff0000u)};                  \
        f32x2 t2 = {__uint_as_float((v).z << 16),                           \
                    __uint_as_float((v).z & 0xffff0000u)};                  \
        f32x2 t3 = {__uint_as_float((v).w << 16),                           \
                    __uint_as_float((v).w & 0xffff0000u)};                  \
        acc2[0] += t0;                                                      \
        acc2[1] += t1;                                                      \
        acc2[2] += t2;                                                      \
        acc2[3] += t3;                                                      \
    } while (0)

template <bool RELU, int BS>
__global__ __launch_bounds__(BS) void k_aggregate(const uint4* __restrict__ Hb4,
                                                  const int* __restrict__ csr,
                                                  const int* __restrict__ off,
                                                  const float* __restrict__ dinv,
                                                  const float* __restrict__ bias,
                                                  void* __restrict__ Aout,
                                                  const float* __restrict__ Wd,
                                                  const float* __restrict__ bd,
                                                  float* __restrict__ out_logp) {
    __shared__ float wds[RELU ? 4 : C * OUTC];       // 32KB Wd stage (layer 2)
    const int tid = threadIdx.x;
    const int gid = (blockIdx.x * BS + tid) >> 4;    // node (16 lanes/node)
    const int sl = tid & 15;                         // 16B chunk of 256B row
    const int grpbase = (tid & 63) & 48;             // group base lane in wave

    if (!RELU) {   // stage Wd [128][64] fp32 into LDS, then ONE barrier
        float4* w4 = (float4*)wds;
        const float4* Wd4 = (const float4*)Wd;
        #pragma unroll
        for (int i = 0; i < (C * OUTC / 4) / BS; ++i)
            w4[tid + i * BS] = Wd4[tid + i * BS];
        __syncthreads();               // no further barriers below
    }
    if (gid >= N_NODES) return;        // tail block (BS=1024 grid is inexact)

    const unsigned sl16 = (unsigned)sl << 4;
    const char* Hbb = (const char*)Hb4;
    const int s0 = off[gid];
    const int e1 = off[gid + 1];
    const int deg = e1 - s0;
    const float di = dinv[gid];

    f32x2 acc2[4];
    #pragma unroll
    for (int j = 0; j < 4; ++j) acc2[j] = (f32x2){0.f, 0.f};

    // self row (already dinv[gid]-scaled)
    {
        uint4 v = *(const uint4*)(Hbb + (((unsigned)gid << 8) + sl16));
        ACC8(v);
    }

    // chunk-preload of adjacency indices: lane sl holds csr[s0 + chunk + sl]
    int myidx = csr[min(s0 + sl, E_EDGES - 1)];
    for (int base = 0; base < deg; base += 16) {
        if (base) myidx = csr[min(s0 + base + sl, E_EDGES - 1)];
        for (int q = 0; q < 16 && base + q < deg; q += 4) {
            const int p1 = base + q + 1, p2 = base + q + 2, p3 = base + q + 3;
            int i0 = __shfl(myidx, grpbase + q + 0);           // p0 < deg by loop cond
            int i1 = (p1 < deg) ? __shfl(myidx, grpbase + q + 1) : ZROW;
            int i2 = (p2 < deg) ? __shfl(myidx, grpbase + q + 2) : ZROW;
            int i3 = (p3 < deg) ? __shfl(myidx, grpbase + q + 3) : ZROW;
            uint4 v0 = *(const uint4*)(Hbb + (((unsigned)i0 << 8) + sl16));
            uint4 v1 = *(const uint4*)(Hbb + (((unsigned)i1 << 8) + sl16));
            uint4 v2 = *(const uint4*)(Hbb + (((unsigned)i2 << 8) + sl16));
            uint4 v3 = *(const uint4*)(Hbb + (((unsigned)i3 << 8) + sl16));
            ACC8(v0);
            ACC8(v1);
            ACC8(v2);
            ACC8(v3);
        }
    }

    float4 b0 = ((const float4*)bias)[sl * 2];
    float4 b1 = ((const float4*)bias)[sl * 2 + 1];
    acc2[0] = acc2[0] * di + (f32x2){b0.x, b0.y};
    acc2[1] = acc2[1] * di + (f32x2){b0.z, b0.w};
    acc2[2] = acc2[2] * di + (f32x2){b1.x, b1.y};
    acc2[3] = acc2[3] * di + (f32x2){b1.z, b1.w};

    if (RELU) {
        #pragma unroll
        for (int j = 0; j < 4; ++j) {
            acc2[j].x = fmaxf(acc2[j].x, 0.f);
            acc2[j].y = fmaxf(acc2[j].y, 0.f);
        }
        // pack 8 channels to bf16 and store 16B (row = 256B by 16 lanes)
        uint4 o;
        o.x = (unsigned)f2bf(acc2[0].x) | ((unsigned)f2bf(acc2[0].y) << 16);
        o.y = (unsigned)f2bf(acc2[1].x) | ((unsigned)f2bf(acc2[1].y) << 16);
        o.z = (unsigned)f2bf(acc2[2].x) | ((unsigned)f2bf(acc2[2].y) << 16);
        o.w = (unsigned)f2bf(acc2[3].x) | ((unsigned)f2bf(acc2[3].y) << 16);
        ((uint4*)Aout)[(size_t)gid * 16 + sl] = o;
    } else {
        float ss = 0.f;
        #pragma unroll
        for (int j = 0; j < 4; ++j) ss += acc2[j].x * acc2[j].x + acc2[j].y * acc2[j].y;
        // reduce over the 16 lanes of this group (xor 1,2,4,8 stays in-group)
        #pragma unroll
        for (int o = 1; o < 16; o <<= 1) ss += __shfl_xor(ss, o);
        const float inv = 1.f / (sqrtf(ss) + 1e-12f);

        // normalized embedding, lane-local 8 channels (registers only)
        float hv[8] = {acc2[0].x * inv, acc2[0].y * inv, acc2[1].x * inv, acc2[1].y * inv,
                       acc2[2].x * inv, acc2[2].y * inv, acc2[3].x * inv, acc2[3].y * inv};

        // store embedding (two float4)
        float4* dst = (float4*)((float*)Aout + (size_t)gid * C + sl * 8);
        dst[0] = make_float4(hv[0], hv[1], hv[2], hv[3]);
        dst[1] = make_float4(hv[4], hv[5], hv[6], hv[7]);

        // fused decode: lane computes cols sl*4..sl*4+3 of its node's logits.
        // channel k owned by lane grpbase+(k>>3), elem k&7 — fully unrolled,
        // register-only hv[]; Wd from LDS.
        float4 bdv = *(const float4*)&bd[sl * 4];
        float g0 = bdv.x, g1 = bdv.y, g2 = bdv.z, g3 = bdv.w;
        #pragma unroll
        for (int k = 0; k < C; ++k) {
            float hk = __shfl(hv[k & 7], grpbase + (k >> 3));
            float4 w = *(const float4*)&wds[k * OUTC + sl * 4];
            g0 = fmaf(hk, w.x, g0);
            g1 = fmaf(hk, w.y, g1);
            g2 = fmaf(hk, w.z, g2);
            g3 = fmaf(hk, w.w, g3);
        }
        // log_softmax over the 64 logits of this node (16 lanes x 4 cols)
        float m = fmaxf(fmaxf(g0, g1), fmaxf(g2, g3));
        #pragma unroll
        for (int o = 1; o < 16; o <<= 1) m = fmaxf(m, __shfl_xor(m, o));
        float s = expf(g0 - m) + expf(g1 - m) + expf(g2 - m) + expf(g3 - m);
        #pragma unroll
        for (int o = 1; o < 16; o <<= 1) s += __shfl_xor(s, o);
        float ls = m + logf(s);
        *(float4*)&out_logp[(size_t)gid * OUTC + sl * 4] =
            make_float4(g0 - ls, g1 - ls, g2 - ls, g3 - ls);
    }
}

extern "C" void kernel_launch(void* const* d_in, const int* in_sizes, int n_in,
                              void* d_out, int out_size, void* d_ws, size_t ws_size,
                              hipStream_t stream) {
    const float* x  = (const float*)d_in[0];
    const int*   ei = (const int*)d_in[1];
    const int* rowi = ei;
    const int* coli = ei + E_EDGES;
    const float* W1 = (const float*)d_in[2];
    const float* b1 = (const float*)d_in[3];
    const float* W2 = (const float*)d_in[4];
    const float* b2 = (const float*)d_in[5];
    const float* Wd = (const float*)d_in[6];
    const float* bd = (const float*)d_in[7];

    float* out_logp = (float*)d_out;                             // [N,64]
    float* out_emb  = (float*)d_out + (long long)N_NODES * OUTC; // [N,128]

    // workspace layout (16B-aligned regions)
    char* p = (char*)d_ws;
    float* dinv = (float*)p;                  p += sizeof(float) * N_NODES;
    unsigned short* Hb = (unsigned short*)p;  p += sizeof(short) * (size_t)(N_NODES + 4) * C; // +4 rows (ZROW pad)
    unsigned short* aggb = (unsigned short*)p; p += sizeof(short) * (size_t)N_NODES * C;      // bf16 h1
    int*   off   = (int*)p;                   p += sizeof(int) * (N_NODES + 4);
    int*   histG = (int*)p;                   p += sizeof(int) * SCM;
    int*   base  = (int*)p;                   p += sizeof(int) * SCM;
    int*   bsum  = (int*)p;                   p += sizeof(int) * 64;
    int*   tmp   = (int*)p;                   p += sizeof(int) * (size_t)E_EDGES;
    int*   csr   = (int*)p;                   p += sizeof(int) * (size_t)E_EDGES;
    uint4* Wp1   = (uint4*)p;                 p += sizeof(uint4) * 2048;
    uint4* Wp2   = (uint4*)p;                 p += sizeof(uint4) * 2048;

    // --- CSR front-end: 4 kernels (histogram+packs, scan, coarse, fine) ---
    k_histpack<<<CB_BLOCKS, CB_THREADS, 0, stream>>>(W1, Wp1, W2, Wp2, (uint4*)Hb,
                                                     coli, histG);
    k_scanA<<<NSB, S1B, 0, stream>>>(histG, base, bsum);
    k_coarse<<<CB_BLOCKS, CB_THREADS, 0, stream>>>(rowi, coli, base, bsum, tmp);
    k_fine<<<NBKT, 256, 0, stream>>>(tmp, base, bsum, csr, off, dinv);

    const int GB = (N_NODES + 63) / 64;            // 1563
    const int AB1 = (N_NODES * 16 + 255) / 256;    // 6250 (exact, BS=256)
    const int AB2 = (N_NODES * 16 + 1023) / 1024;  // 1563 (tail-guarded, BS=1024)
    // --- conv1: H1b = (x@W1)*dinv -> gather-agg -> relu -> bf16 aggb ---
    k_gemm_mfma<false><<<GB, 256, 0, stream>>>(x, Wp1, dinv, Hb);
    k_aggregate<true, 256><<<AB1, 256, 0, stream>>>((const uint4*)Hb, csr, off, dinv, b1, aggb,
                                                    nullptr, nullptr, nullptr);
    // --- conv2: H2b = (aggb@W2)*dinv -> gather-agg -> normalize -> out_emb
    //            + fused decode -> out_logp (Wd in LDS, 1024-thread blocks) ---
    k_gemm_mfma<true><<<GB, 256, 0, stream>>>(aggb, Wp2, dinv, Hb);
    k_aggregate<false, 1024><<<AB2, 1024, 0, stream>>>((const uint4*)Hb, csr, off, dinv, b2, out_emb,
                                                       Wd, bd, out_logp);
}

// Round 13
// 366.968 us; speedup vs baseline: 1.1060x; 1.0495x over previous
//
#include <hip/hip_runtime.h>

#define N_NODES 100000
#define E_EDGES 1600000
#define C 128     // IN_C = H1 = H2
#define OUTC 64
#define ZROW N_NODES   // index of the dedicated all-zero Hb row

// ---- CSR build (two-level counting sort) constants ----
#define NPB 128                                   // nodes per bucket (dest >> 7)
#define NBKT ((N_NODES + NPB - 1) / NPB)          // 782 buckets
#define CB_BLOCKS 64                              // phase A/C blocks
#define CB_THREADS 1024
#define EPB ((E_EDGES + CB_BLOCKS - 1) / CB_BLOCKS)  // 25000 edges/block
#define SCM (NBKT * CB_BLOCKS)                    // 50048 scan elements
#define S1B 1024
#define NSB ((SCM + S1B - 1) / S1B)               // 49

typedef __attribute__((ext_vector_type(8))) short bf16x8;
typedef __attribute__((ext_vector_type(4))) float f32x4;
typedef __attribute__((ext_vector_type(2))) float f32x2;

// rne float->bf16
__device__ inline unsigned short f2bf(float x) {
    unsigned u = __float_as_uint(x);
    unsigned r = u + 0x7fffu + ((u >> 16) & 1u);
    return (unsigned short)(r >> 16);
}

__device__ __forceinline__ void packW_body(const float* __restrict__ W,
                                           uint4* __restrict__ Wp, int gtid) {
    // frag (t,s,lane): B[k = s*32 + (lane>>4)*8 + j][n = t*16 + (lane&15)]
    int L = gtid & 63;
    int ts = gtid >> 6;                          // 0..31
    int t = ts >> 2, s = ts & 3;
    int n = t * 16 + (L & 15);
    int k0 = s * 32 + (L >> 4) * 8;
    unsigned e[8];
    #pragma unroll
    for (int j = 0; j < 8; ++j) e[j] = f2bf(W[(k0 + j) * C + n]);
    uint4 v;
    v.x = e[0] | (e[1] << 16);
    v.y = e[2] | (e[3] << 16);
    v.z = e[4] | (e[5] << 16);
    v.w = e[6] | (e[7] << 16);
    Wp[gtid] = v;
}

// pack Wd [128][64] -> 1024 bf16 B-frags (4 col-tiles x 4 k-steps)
__device__ __forceinline__ void packWd_body(const float* __restrict__ Wd,
                                            uint4* __restrict__ Wpd, int gtid) {
    int L = gtid & 63;
    int ts = gtid >> 6;                          // 0..15
    int t = ts >> 2, s = ts & 3;
    int n = t * 16 + (L & 15);                   // 0..63
    int k0 = s * 32 + (L >> 4) * 8;
    unsigned e[8];
    #pragma unroll
    for (int j = 0; j < 8; ++j) e[j] = f2bf(Wd[(k0 + j) * OUTC + n]);
    uint4 v;
    v.x = e[0] | (e[1] << 16);
    v.y = e[2] | (e[3] << 16);
    v.z = e[4] | (e[5] << 16);
    v.w = e[6] | (e[7] << 16);
    Wpd[gtid] = v;
}

// exclusive scan of bsum[NSB] computed by the first wave into sbp[] (LDS)
__device__ __forceinline__ void bsum_scan_wave(const int* __restrict__ bsum,
                                               int* __restrict__ sbp, int t) {
    if (t < 64) {
        int v = (t < NSB) ? bsum[t] : 0;
        int x = v;
        #pragma unroll
        for (int o = 1; o < 64; o <<= 1) {
            int y = __shfl_up(x, o);
            if (t >= o) x += y;
        }
        sbp[t] = x - v;                          // exclusive prefix
    }
}

// ---------------- Phase A: histogram + weight packs + ZROW (all independent) ----------------
__global__ __launch_bounds__(CB_THREADS) void k_histpack(const float* __restrict__ W1,
                                                         uint4* __restrict__ Wp1,
                                                         const float* __restrict__ W2,
                                                         uint4* __restrict__ Wp2,
                                                         const float* __restrict__ Wd,
                                                         uint4* __restrict__ Wpd,
                                                         uint4* __restrict__ Hbz,
                                                         const int* __restrict__ coli,
                                                         int* __restrict__ histG) {
    __shared__ int h[NBKT];
    const int b = blockIdx.x;
    const int t = threadIdx.x;
    // side work on the first 6 blocks (no cross-block dependency)
    if (b < 2)       packW_body(W1, Wp1, b * 1024 + t);
    else if (b < 4)  packW_body(W2, Wp2, (b - 2) * 1024 + t);
    else if (b == 4 && t < 16)
        Hbz[(size_t)ZROW * 16 + t] = make_uint4(0u, 0u, 0u, 0u);
    else if (b == 5) packWd_body(Wd, Wpd, t);

    for (int i = t; i < NBKT; i += CB_THREADS) h[i] = 0;
    __syncthreads();
    const int e0 = b * EPB;
    const int e1 = min(e0 + EPB, E_EDGES);
    for (int e = e0 + t; e < e1; e += CB_THREADS)
        atomicAdd(&h[coli[e] >> 7], 1);
    __syncthreads();
    for (int i = t; i < NBKT; i += CB_THREADS)
        histG[i * CB_BLOCKS + b] = h[i];             // bucket-major
}

// ---------------- Phase B: per-scan-block exclusive scan (base stays block-local) ----------------
__global__ __launch_bounds__(S1B) void k_scanA(const int* __restrict__ in,
                                               int* __restrict__ base,
                                               int* __restrict__ bsum) {
    __shared__ int s[S1B];
    int tid = threadIdx.x;
    int i = blockIdx.x * S1B + tid;
    int v = (i < SCM) ? in[i] : 0;
    s[tid] = v;
    __syncthreads();
    #pragma unroll
    for (int o = 1; o < S1B; o <<= 1) {
        int t = (tid >= o) ? s[tid - o] : 0;
        __syncthreads();
        s[tid] += t;
        __syncthreads();
    }
    if (i < SCM) base[i] = s[tid] - v;               // block-local exclusive
    if (tid == S1B - 1) bsum[blockIdx.x] = s[tid];   // block total
}

// ---------------- Phase C: coarse scatter (global prefix added on the fly) ----------------
__global__ __launch_bounds__(CB_THREADS) void k_coarse(const int* __restrict__ rowi,
                                                       const int* __restrict__ coli,
                                                       const int* __restrict__ base,
                                                       const int* __restrict__ bsum,
                                                       int* __restrict__ tmp) {
    __shared__ int cur[NBKT];
    __shared__ int sbp[64];
    const int b = blockIdx.x;
    const int t = threadIdx.x;
    bsum_scan_wave(bsum, sbp, t);
    __syncthreads();
    for (int i = t; i < NBKT; i += CB_THREADS) {
        int el = i * CB_BLOCKS + b;
        cur[i] = base[el] + sbp[el >> 10];
    }
    __syncthreads();
    const int e0 = b * EPB;
    const int e1 = min(e0 + EPB, E_EDGES);
    for (int e = e0 + t; e < e1; e += CB_THREADS) {
        int c = coli[e];
        int pos = atomicAdd(&cur[c >> 7], 1);
        tmp[pos] = rowi[e] | ((c & 127) << 17);
    }
}

// ---------------- Phase D: fine counting-sort + off[] + dinv[] ----------------
__global__ __launch_bounds__(256) void k_fine(const int* __restrict__ tmp,
                                              const int* __restrict__ base,
                                              const int* __restrict__ bsum,
                                              int* __restrict__ csr,
                                              int* __restrict__ off,
                                              float* __restrict__ dinv) {
    __shared__ int hist[NPB];
    __shared__ int scn[NPB];
    __shared__ int sbp[64];
    const int b = blockIdx.x;
    const int tid = threadIdx.x;
    bsum_scan_wave(bsum, sbp, tid);
    if (tid < NPB) hist[tid] = 0;
    __syncthreads();
    const int el0 = b * CB_BLOCKS;
    const int bb = base[el0] + sbp[el0 >> 10];
    const int be = (b + 1 < NBKT)
                 ? (base[(b + 1) * CB_BLOCKS] + sbp[((b + 1) * CB_BLOCKS) >> 10])
                 : E_EDGES;
    for (int i = bb + tid; i < be; i += 256)
        atomicAdd(&hist[(tmp[i] >> 17) & 127], 1);
    __syncthreads();
    if (tid < NPB) scn[tid] = hist[tid];
    __syncthreads();
    #pragma unroll
    for (int o = 1; o < NPB; o <<= 1) {
        int t = (tid < NPB && tid >= o) ? scn[tid - o] : 0;
        __syncthreads();
        if (tid < NPB) scn[tid] += t;
        __syncthreads();
    }
    if (tid < NPB) {
        int node = b * NPB + tid;
        int excl = scn[tid] - hist[tid];
        if (node < N_NODES) {
            off[node] = bb + excl;
            dinv[node] = rsqrtf((float)(hist[tid] + 1));   // +1 self-loop
        }
        scn[tid] = bb + excl;
    }
    if (b == NBKT - 1 && tid == 0) off[N_NODES] = E_EDGES;
    __syncthreads();
    for (int i = bb + tid; i < be; i += 256) {
        int v = tmp[i];
        int pos = atomicAdd(&scn[(v >> 17) & 127], 1);
        csr[pos] = v & 0x1ffff;
    }
}

// ---------------- MFMA encoder GEMM [N,128]@[128,128] -> bf16, rows scaled by dinv ----------
template <bool BF16IN>
__global__ __launch_bounds__(256) void k_gemm_mfma(const void* __restrict__ Xv,
                                                   const uint4* __restrict__ Wp,
                                                   const float* __restrict__ dinv,
                                                   unsigned short* __restrict__ Hb) {
    __shared__ float xs[64][C];        // 32 KB, reused as bf16 out-staging
    __shared__ float sd[64];
    const int t = threadIdx.x;
    const int r0 = blockIdx.x * 64;
    const bool full = (r0 + 64 <= N_NODES);

    if (BF16IN) {   // stage 64x128 bf16 tile (coalesced uint4)
        const uint4* X4 = (const uint4*)((const unsigned short*)Xv + (size_t)r0 * C);
        uint4* s4 = (uint4*)xs;        // first 16KB
        #pragma unroll
        for (int i = 0; i < 4; ++i) {
            int li = t + i * 256;      // 0..1023, row = li>>4
            if (full || (r0 + (li >> 4) < N_NODES)) s4[li] = X4[li];
            else s4[li] = make_uint4(0u, 0u, 0u, 0u);
        }
    } else {        // stage 64x128 fp32 tile (coalesced float4)
        const float4* X4 = (const float4*)((const float*)Xv + (size_t)r0 * C);
        float4* s4 = (float4*)xs;
        #pragma unroll
        for (int i = 0; i < 8; ++i) {
            int li = t + i * 256;
            if (full || (r0 + (li >> 5) < N_NODES)) s4[li] = X4[li];
            else s4[li] = make_float4(0.f, 0.f, 0.f, 0.f);
        }
    }
    if (t < 64) sd[t] = (r0 + t < N_NODES) ? dinv[r0 + t] : 1.f;
    __syncthreads();

    const int w = t >> 6;              // wave 0..3
    const int lane = t & 63;
    const int m = lane & 15;
    const int q = lane >> 4;
    const int arow = w * 16 + m;       // A row this lane reads

    f32x4 acc[8];
    #pragma unroll
    for (int i = 0; i < 8; ++i) acc[i] = (f32x4){0.f, 0.f, 0.f, 0.f};

    const bf16x8* Wp8 = (const bf16x8*)Wp;
    const unsigned short* xb = (const unsigned short*)xs;
    #pragma unroll
    for (int s = 0; s < 4; ++s) {
        const int k0 = s * 32 + q * 8;
        bf16x8 a;
        if (BF16IN) {
            a = *(const bf16x8*)&xb[arow * C + k0];
        } else {
            float4 va = *(const float4*)&xs[arow][k0];
            float4 vb = *(const float4*)&xs[arow][k0 + 4];
            a[0] = (short)f2bf(va.x); a[1] = (short)f2bf(va.y);
            a[2] = (short)f2bf(va.z); a[3] = (short)f2bf(va.w);
            a[4] = (short)f2bf(vb.x); a[5] = (short)f2bf(vb.y);
            a[6] = (short)f2bf(vb.z); a[7] = (short)f2bf(vb.w);
        }
        #pragma unroll
        for (int tt = 0; tt < 8; ++tt) {
            bf16x8 b = Wp8[(tt * 4 + s) * 64 + lane];
            acc[tt] = __builtin_amdgcn_mfma_f32_16x16x32_bf16(a, b, acc[tt], 0, 0, 0);
        }
    }

    __syncthreads();                   // all waves done reading xs
    unsigned short* hb = (unsigned short*)xs;   // 64x128 bf16 staging
    const int lrb = w * 16 + q * 4;
    #pragma unroll
    for (int r = 0; r < 4; ++r) {
        float sc = sd[lrb + r];
        #pragma unroll
        for (int tt = 0; tt < 8; ++tt)
            hb[(lrb + r) * C + tt * 16 + m] = f2bf(acc[tt][r] * sc);
    }
    __syncthreads();

    // coalesced store: 64x128 bf16 = 1024 uint4
    const uint4* src = (const uint4*)hb;
    uint4* dst = (uint4*)(Hb + (size_t)r0 * C);
    #pragma unroll
    for (int i = 0; i < 4; ++i) {
        int li = t + i * 256;
        if (full || (r0 + (li >> 4) < N_NODES)) dst[li] = src[li];
    }
}

// ---------------- fused aggregation over bf16 scaled rows (round-8 form) ----------------
// 16 lanes per node (4 nodes per wave). Lane sl owns channels sl*8..sl*8+7.
// RELU=true  (layer 1): out = relu(agg*di + b) -> bf16 [N,128].
// RELU=false (layer 2): out = normalized embedding fp32 -> out_emb. No decode
//   here: the shfl+LDS-Wd fused decode (rounds 9-12) was DS-pipe-bound
//   (each 16-lane group reads all 32KB of Wd: 3.3GB LDS traffic = +44us).
#define ACC8(v)                                                             \
    do {                                                                    \
        f32x2 t0 = {__uint_as_float((v).x << 16),                           \
                    __uint_as_float((v).x & 0xffff0000u)};                  \
        f32x2 t1 = {__uint_as_float((v).y << 16),                           \
                    __uint_as_float((v).y & 0xffff0000u)};                  \
        f32x2 t2 = {__uint_as_float((v).z << 16),                           \
                    __uint_as_float((v).z & 0xffff0000u)};                  \
        f32x2 t3 = {__uint_as_float((v).w << 16),                           \
                    __uint_as_float((v).w & 0xffff0000u)};                  \
        acc2[0] += t0;                                                      \
        acc2[1] += t1;                                                      \
        acc2[2] += t2;                                                      \
        acc2[3] += t3;                                                      \
    } while (0)

template <bool RELU>
__global__ __launch_bounds__(256) void k_aggregate(const uint4* __restrict__ Hb4,
                                                   const int* __restrict__ csr,
                                                   const int* __restrict__ off,
                                                   const float* __restrict__ dinv,
                                                   const float* __restrict__ bias,
                                                   void* __restrict__ Aout) {
    const int tid = threadIdx.x;
    const int gid = (blockIdx.x * 256 + tid) >> 4;   // node (16 lanes/node); grid exact
    if (gid >= N_NODES) return;                      // never taken (exact grid)
    const int sl = tid & 15;                         // 16B chunk of 256B row
    const int grpbase = (tid & 63) & 48;             // group base lane in wave
    const unsigned sl16 = (unsigned)sl << 4;
    const char* Hbb = (const char*)Hb4;
    const int s0 = off[gid];
    const int e1 = off[gid + 1];
    const int deg = e1 - s0;
    const float di = dinv[gid];

    f32x2 acc2[4];
    #pragma unroll
    for (int j = 0; j < 4; ++j) acc2[j] = (f32x2){0.f, 0.f};

    // self row (already dinv[gid]-scaled)
    {
        uint4 v = *(const uint4*)(Hbb + (((unsigned)gid << 8) + sl16));
        ACC8(v);
    }

    // chunk-preload of adjacency indices: lane sl holds csr[s0 + chunk + sl]
    int myidx = csr[min(s0 + sl, E_EDGES - 1)];
    for (int base = 0; base < deg; base += 16) {
        if (base) myidx = csr[min(s0 + base + sl, E_EDGES - 1)];
        for (int q = 0; q < 16 && base + q < deg; q += 4) {
            const int p1 = base + q + 1, p2 = base + q + 2, p3 = base + q + 3;
            int i0 = __shfl(myidx, grpbase + q + 0);           // p0 < deg by loop cond
            int i1 = (p1 < deg) ? __shfl(myidx, grpbase + q + 1) : ZROW;
            int i2 = (p2 < deg) ? __shfl(myidx, grpbase + q + 2) : ZROW;
            int i3 = (p3 < deg) ? __shfl(myidx, grpbase + q + 3) : ZROW;
            uint4 v0 = *(const uint4*)(Hbb + (((unsigned)i0 << 8) + sl16));
            uint4 v1 = *(const uint4*)(Hbb + (((unsigned)i1 << 8) + sl16));
            uint4 v2 = *(const uint4*)(Hbb + (((unsigned)i2 << 8) + sl16));
            uint4 v3 = *(const uint4*)(Hbb + (((unsigned)i3 << 8) + sl16));
            ACC8(v0);
            ACC8(v1);
            ACC8(v2);
            ACC8(v3);
        }
    }

    float4 b0 = ((const float4*)bias)[sl * 2];
    float4 b1 = ((const float4*)bias)[sl * 2 + 1];
    acc2[0] = acc2[0] * di + (f32x2){b0.x, b0.y};
    acc2[1] = acc2[1] * di + (f32x2){b0.z, b0.w};
    acc2[2] = acc2[2] * di + (f32x2){b1.x, b1.y};
    acc2[3] = acc2[3] * di + (f32x2){b1.z, b1.w};

    if (RELU) {
        #pragma unroll
        for (int j = 0; j < 4; ++j) {
            acc2[j].x = fmaxf(acc2[j].x, 0.f);
            acc2[j].y = fmaxf(acc2[j].y, 0.f);
        }
        // pack 8 channels to bf16 and store 16B (row = 256B by 16 lanes)
        uint4 o;
        o.x = (unsigned)f2bf(acc2[0].x) | ((unsigned)f2bf(acc2[0].y) << 16);
        o.y = (unsigned)f2bf(acc2[1].x) | ((unsigned)f2bf(acc2[1].y) << 16);
        o.z = (unsigned)f2bf(acc2[2].x) | ((unsigned)f2bf(acc2[2].y) << 16);
        o.w = (unsigned)f2bf(acc2[3].x) | ((unsigned)f2bf(acc2[3].y) << 16);
        ((uint4*)Aout)[(size_t)gid * 16 + sl] = o;
    } else {
        float ss = 0.f;
        #pragma unroll
        for (int j = 0; j < 4; ++j) ss += acc2[j].x * acc2[j].x + acc2[j].y * acc2[j].y;
        // reduce over the 16 lanes of this group (xor 1,2,4,8 stays in-group)
        #pragma unroll
        for (int o = 1; o < 16; o <<= 1) ss += __shfl_xor(ss, o);
        const float inv = 1.f / (sqrtf(ss) + 1e-12f);
        // store normalized embedding: lane sl writes channels sl*8..sl*8+7
        float4* dst = (float4*)((float*)Aout + (size_t)gid * C + sl * 8);
        dst[0] = make_float4(acc2[0].x * inv, acc2[0].y * inv,
                             acc2[1].x * inv, acc2[1].y * inv);
        dst[1] = make_float4(acc2[2].x * inv, acc2[2].y * inv,
                             acc2[3].x * inv, acc2[3].y * inv);
    }
}

// ---------------- MFMA decode: logp = log_softmax(E@Wd + bd) ----------------
// 64-row tile, 4 waves; wave w owns rows w*16..w*16+15. 4 col-tiles x 4
// k-steps of 16x16x32 MFMA against pre-packed bf16 Wd. C/D layout (same as
// k_gemm_mfma): row = w*16 + q*4 + reg, col = tt*16 + m. Row softmax = max/
// sum over 4 own cols + shfl_xor(1,2,4,8) across the 16-lane m-group.
__global__ __launch_bounds__(256) void k_decode_mfma(const float* __restrict__ E,
                                                     const uint4* __restrict__ Wpd,
                                                     const float* __restrict__ bd,
                                                     float* __restrict__ out_logp) {
    __shared__ float xs[64][C];        // 32 KB emb staging
    const int t = threadIdx.x;
    const int r0 = blockIdx.x * 64;
    const bool full = (r0 + 64 <= N_NODES);
    {
        const float4* X4 = (const float4*)(E + (size_t)r0 * C);
        float4* s4 = (float4*)xs;
        #pragma unroll
        for (int i = 0; i < 8; ++i) {
            int li = t + i * 256;
            if (full || (r0 + (li >> 5) < N_NODES)) s4[li] = X4[li];
            else s4[li] = make_float4(0.f, 0.f, 0.f, 0.f);
        }
    }
    __syncthreads();

    const int w = t >> 6;
    const int lane = t & 63;
    const int m = lane & 15;
    const int q = lane >> 4;
    const int arow = w * 16 + m;

    f32x4 acc[4];
    #pragma unroll
    for (int i = 0; i < 4; ++i) acc[i] = (f32x4){0.f, 0.f, 0.f, 0.f};

    const bf16x8* Wp8 = (const bf16x8*)Wpd;
    #pragma unroll
    for (int s = 0; s < 4; ++s) {
        const int k0 = s * 32 + q * 8;
        float4 va = *(const float4*)&xs[arow][k0];
        float4 vb = *(const float4*)&xs[arow][k0 + 4];
        bf16x8 a;
        a[0] = (short)f2bf(va.x); a[1] = (short)f2bf(va.y);
        a[2] = (short)f2bf(va.z); a[3] = (short)f2bf(va.w);
        a[4] = (short)f2bf(vb.x); a[5] = (short)f2bf(vb.y);
        a[6] = (short)f2bf(vb.z); a[7] = (short)f2bf(vb.w);
        #pragma unroll
        for (int tt = 0; tt < 4; ++tt) {
            bf16x8 b = Wp8[(tt * 4 + s) * 64 + lane];
            acc[tt] = __builtin_amdgcn_mfma_f32_16x16x32_bf16(a, b, acc[tt], 0, 0, 0);
        }
    }

    // bias per own column (col = tt*16 + m)
    float bdv[4];
    #pragma unroll
    for (int tt = 0; tt < 4; ++tt) bdv[tt] = bd[tt * 16 + m];

    #pragma unroll
    for (int reg = 0; reg < 4; ++reg) {
        int row = r0 + w * 16 + q * 4 + reg;
        float g0 = acc[0][reg] + bdv[0];
        float g1 = acc[1][reg] + bdv[1];
        float g2 = acc[2][reg] + bdv[2];
        float g3 = acc[3][reg] + bdv[3];
        float mx = fmaxf(fmaxf(g0, g1), fmaxf(g2, g3));
        #pragma unroll
        for (int o = 1; o < 16; o <<= 1) mx = fmaxf(mx, __shfl_xor(mx, o));
        float s = expf(g0 - mx) + expf(g1 - mx) + expf(g2 - mx) + expf(g3 - mx);
        #pragma unroll
        for (int o = 1; o < 16; o <<= 1) s += __shfl_xor(s, o);
        float ls = mx + logf(s);
        if (row < N_NODES) {
            float* op = &out_logp[(size_t)row * OUTC + m];
            op[0]  = g0 - ls;
            op[16] = g1 - ls;
            op[32] = g2 - ls;
            op[48] = g3 - ls;
        }
    }
}

extern "C" void kernel_launch(void* const* d_in, const int* in_sizes, int n_in,
                              void* d_out, int out_size, void* d_ws, size_t ws_size,
                              hipStream_t stream) {
    const float* x  = (const float*)d_in[0];
    const int*   ei = (const int*)d_in[1];
    const int* rowi = ei;
    const int* coli = ei + E_EDGES;
    const float* W1 = (const float*)d_in[2];
    const float* b1 = (const float*)d_in[3];
    const float* W2 = (const float*)d_in[4];
    const float* b2 = (const float*)d_in[5];
    const float* Wd = (const float*)d_in[6];
    const float* bd = (const float*)d_in[7];

    float* out_logp = (float*)d_out;                             // [N,64]
    float* out_emb  = (float*)d_out + (long long)N_NODES * OUTC; // [N,128]

    // workspace layout (16B-aligned regions)
    char* p = (char*)d_ws;
    float* dinv = (float*)p;                  p += sizeof(float) * N_NODES;
    unsigned short* Hb = (unsigned short*)p;  p += sizeof(short) * (size_t)(N_NODES + 4) * C; // +4 rows (ZROW pad)
    unsigned short* aggb = (unsigned short*)p; p += sizeof(short) * (size_t)N_NODES * C;      // bf16 h1
    int*   off   = (int*)p;                   p += sizeof(int) * (N_NODES + 4);
    int*   histG = (int*)p;                   p += sizeof(int) * SCM;
    int*   base  = (int*)p;                   p += sizeof(int) * SCM;
    int*   bsum  = (int*)p;                   p += sizeof(int) * 64;
    int*   tmp   = (int*)p;                   p += sizeof(int) * (size_t)E_EDGES;
    int*   csr   = (int*)p;                   p += sizeof(int) * (size_t)E_EDGES;
    uint4* Wp1   = (uint4*)p;                 p += sizeof(uint4) * 2048;
    uint4* Wp2   = (uint4*)p;                 p += sizeof(uint4) * 2048;
    uint4* Wpd   = (uint4*)p;                 p += sizeof(uint4) * 1024;

    // --- CSR front-end: 4 kernels (histogram+packs, scan, coarse, fine) ---
    k_histpack<<<CB_BLOCKS, CB_THREADS, 0, stream>>>(W1, Wp1, W2, Wp2, Wd, Wpd,
                                                     (uint4*)Hb, coli, histG);
    k_scanA<<<NSB, S1B, 0, stream>>>(histG, base, bsum);
    k_coarse<<<CB_BLOCKS, CB_THREADS, 0, stream>>>(rowi, coli, base, bsum, tmp);
    k_fine<<<NBKT, 256, 0, stream>>>(tmp, base, bsum, csr, off, dinv);

    const int GB = (N_NODES + 63) / 64;          // 1563
    const int AB = (N_NODES * 16 + 255) / 256;   // 6250 (16 lanes per node, exact)
    // --- conv1: H1b = (x@W1)*dinv -> gather-agg -> relu -> bf16 aggb ---
    k_gemm_mfma<false><<<GB, 256, 0, stream>>>(x, Wp1, dinv, Hb);
    k_aggregate<true><<<AB, 256, 0, stream>>>((const uint4*)Hb, csr, off, dinv, b1, aggb);
    // --- conv2: H2b = (aggb@W2)*dinv -> gather-agg -> normalize -> out_emb ---
    k_gemm_mfma<true><<<GB, 256, 0, stream>>>(aggb, Wp2, dinv, Hb);
    k_aggregate<false><<<AB, 256, 0, stream>>>((const uint4*)Hb, csr, off, dinv, b2, out_emb);
    // --- MFMA decode: logp = log_softmax(out_emb@Wd + bd) ---
    k_decode_mfma<<<GB, 256, 0, stream>>>(out_emb, Wpd, bd, out_logp);
}

// Round 14
// 360.834 us; speedup vs baseline: 1.1248x; 1.0170x over previous
//
#include <hip/hip_runtime.h>

#define N_NODES 100000
#define E_EDGES 1600000
#define C 128     // IN_C = H1 = H2
#define OUTC 64
#define ZROW N_NODES   // index of the dedicated all-zero Hb row

// ---- CSR build (two-level counting sort) constants ----
#define NPB 128                                   // nodes per bucket (dest >> 7)
#define NBKT ((N_NODES + NPB - 1) / NPB)          // 782 buckets
#define CB_BLOCKS 64                              // phase A/C blocks
#define CB_THREADS 1024
#define EPB ((E_EDGES + CB_BLOCKS - 1) / CB_BLOCKS)  // 25000 edges/block
#define SCM (NBKT * CB_BLOCKS)                    // 50048 scan elements
#define S1B 1024
#define NSB ((SCM + S1B - 1) / S1B)               // 49

typedef __attribute__((ext_vector_type(8))) short bf16x8;
typedef __attribute__((ext_vector_type(4))) float f32x4;
typedef __attribute__((ext_vector_type(2))) float f32x2;

// rne float->bf16
__device__ inline unsigned short f2bf(float x) {
    unsigned u = __float_as_uint(x);
    unsigned r = u + 0x7fffu + ((u >> 16) & 1u);
    return (unsigned short)(r >> 16);
}

__device__ __forceinline__ void packW_body(const float* __restrict__ W,
                                           uint4* __restrict__ Wp, int gtid) {
    // frag (t,s,lane): B[k = s*32 + (lane>>4)*8 + j][n = t*16 + (lane&15)]
    int L = gtid & 63;
    int ts = gtid >> 6;                          // 0..31
    int t = ts >> 2, s = ts & 3;
    int n = t * 16 + (L & 15);
    int k0 = s * 32 + (L >> 4) * 8;
    unsigned e[8];
    #pragma unroll
    for (int j = 0; j < 8; ++j) e[j] = f2bf(W[(k0 + j) * C + n]);
    uint4 v;
    v.x = e[0] | (e[1] << 16);
    v.y = e[2] | (e[3] << 16);
    v.z = e[4] | (e[5] << 16);
    v.w = e[6] | (e[7] << 16);
    Wp[gtid] = v;
}

// pack Wd [128][64] -> 1024 bf16 B-frags (4 col-tiles x 4 k-steps)
__device__ __forceinline__ void packWd_body(const float* __restrict__ Wd,
                                            uint4* __restrict__ Wpd, int gtid) {
    int L = gtid & 63;
    int ts = gtid >> 6;                          // 0..15
    int t = ts >> 2, s = ts & 3;
    int n = t * 16 + (L & 15);                   // 0..63
    int k0 = s * 32 + (L >> 4) * 8;
    unsigned e[8];
    #pragma unroll
    for (int j = 0; j < 8; ++j) e[j] = f2bf(Wd[(k0 + j) * OUTC + n]);
    uint4 v;
    v.x = e[0] | (e[1] << 16);
    v.y = e[2] | (e[3] << 16);
    v.z = e[4] | (e[5] << 16);
    v.w = e[6] | (e[7] << 16);
    Wpd[gtid] = v;
}

// exclusive scan of bsum[NSB] computed by the first wave into sbp[] (LDS)
__device__ __forceinline__ void bsum_scan_wave(const int* __restrict__ bsum,
                                               int* __restrict__ sbp, int t) {
    if (t < 64) {
        int v = (t < NSB) ? bsum[t] : 0;
        int x = v;
        #pragma unroll
        for (int o = 1; o < 64; o <<= 1) {
            int y = __shfl_up(x, o);
            if (t >= o) x += y;
        }
        sbp[t] = x - v;                          // exclusive prefix
    }
}

// ---------------- Phase A: histogram + weight packs + ZROW (all independent) ----------------
__global__ __launch_bounds__(CB_THREADS) void k_histpack(const float* __restrict__ W1,
                                                         uint4* __restrict__ Wp1,
                                                         const float* __restrict__ W2,
                                                         uint4* __restrict__ Wp2,
                                                         const float* __restrict__ Wd,
                                                         uint4* __restrict__ Wpd,
                                                         uint4* __restrict__ Hbz,
                                                         const int* __restrict__ coli,
                                                         int* __restrict__ histG) {
    __shared__ int h[NBKT];
    const int b = blockIdx.x;
    const int t = threadIdx.x;
    // side work on the first 6 blocks (no cross-block dependency)
    if (b < 2)       packW_body(W1, Wp1, b * 1024 + t);
    else if (b < 4)  packW_body(W2, Wp2, (b - 2) * 1024 + t);
    else if (b == 4 && t < 16)
        Hbz[(size_t)ZROW * 16 + t] = make_uint4(0u, 0u, 0u, 0u);
    else if (b == 5) packWd_body(Wd, Wpd, t);

    for (int i = t; i < NBKT; i += CB_THREADS) h[i] = 0;
    __syncthreads();
    const int e0 = b * EPB;
    const int e1 = min(e0 + EPB, E_EDGES);
    for (int e = e0 + t; e < e1; e += CB_THREADS)
        atomicAdd(&h[coli[e] >> 7], 1);
    __syncthreads();
    for (int i = t; i < NBKT; i += CB_THREADS)
        histG[i * CB_BLOCKS + b] = h[i];             // bucket-major
}

// ---------------- Phase B: per-scan-block exclusive scan (base stays block-local) ----------------
__global__ __launch_bounds__(S1B) void k_scanA(const int* __restrict__ in,
                                               int* __restrict__ base,
                                               int* __restrict__ bsum) {
    __shared__ int s[S1B];
    int tid = threadIdx.x;
    int i = blockIdx.x * S1B + tid;
    int v = (i < SCM) ? in[i] : 0;
    s[tid] = v;
    __syncthreads();
    #pragma unroll
    for (int o = 1; o < S1B; o <<= 1) {
        int t = (tid >= o) ? s[tid - o] : 0;
        __syncthreads();
        s[tid] += t;
        __syncthreads();
    }
    if (i < SCM) base[i] = s[tid] - v;               // block-local exclusive
    if (tid == S1B - 1) bsum[blockIdx.x] = s[tid];   // block total
}

// ---------------- Phase C: coarse scatter (global prefix added on the fly) ----------------
__global__ __launch_bounds__(CB_THREADS) void k_coarse(const int* __restrict__ rowi,
                                                       const int* __restrict__ coli,
                                                       const int* __restrict__ base,
                                                       const int* __restrict__ bsum,
                                                       int* __restrict__ tmp) {
    __shared__ int cur[NBKT];
    __shared__ int sbp[64];
    const int b = blockIdx.x;
    const int t = threadIdx.x;
    bsum_scan_wave(bsum, sbp, t);
    __syncthreads();
    for (int i = t; i < NBKT; i += CB_THREADS) {
        int el = i * CB_BLOCKS + b;
        cur[i] = base[el] + sbp[el >> 10];
    }
    __syncthreads();
    const int e0 = b * EPB;
    const int e1 = min(e0 + EPB, E_EDGES);
    for (int e = e0 + t; e < e1; e += CB_THREADS) {
        int c = coli[e];
        int pos = atomicAdd(&cur[c >> 7], 1);
        tmp[pos] = rowi[e] | ((c & 127) << 17);
    }
}

// ---------------- Phase D: fine counting-sort + off[] + dinv[] ----------------
__global__ __launch_bounds__(256) void k_fine(const int* __restrict__ tmp,
                                              const int* __restrict__ base,
                                              const int* __restrict__ bsum,
                                              int* __restrict__ csr,
                                              int* __restrict__ off,
                                              float* __restrict__ dinv) {
    __shared__ int hist[NPB];
    __shared__ int scn[NPB];
    __shared__ int sbp[64];
    const int b = blockIdx.x;
    const int tid = threadIdx.x;
    bsum_scan_wave(bsum, sbp, tid);
    if (tid < NPB) hist[tid] = 0;
    __syncthreads();
    const int el0 = b * CB_BLOCKS;
    const int bb = base[el0] + sbp[el0 >> 10];
    const int be = (b + 1 < NBKT)
                 ? (base[(b + 1) * CB_BLOCKS] + sbp[((b + 1) * CB_BLOCKS) >> 10])
                 : E_EDGES;
    for (int i = bb + tid; i < be; i += 256)
        atomicAdd(&hist[(tmp[i] >> 17) & 127], 1);
    __syncthreads();
    if (tid < NPB) scn[tid] = hist[tid];
    __syncthreads();
    #pragma unroll
    for (int o = 1; o < NPB; o <<= 1) {
        int t = (tid < NPB && tid >= o) ? scn[tid - o] : 0;
        __syncthreads();
        if (tid < NPB) scn[tid] += t;
        __syncthreads();
    }
    if (tid < NPB) {
        int node = b * NPB + tid;
        int excl = scn[tid] - hist[tid];
        if (node < N_NODES) {
            off[node] = bb + excl;
            dinv[node] = rsqrtf((float)(hist[tid] + 1));   // +1 self-loop
        }
        scn[tid] = bb + excl;
    }
    if (b == NBKT - 1 && tid == 0) off[N_NODES] = E_EDGES;
    __syncthreads();
    for (int i = bb + tid; i < be; i += 256) {
        int v = tmp[i];
        int pos = atomicAdd(&scn[(v >> 17) & 127], 1);
        csr[pos] = v & 0x1ffff;
    }
}

// ---------------- MFMA encoder GEMM [N,128]@[128,128] -> bf16, rows scaled by dinv ----------
template <bool BF16IN>
__global__ __launch_bounds__(256) void k_gemm_mfma(const void* __restrict__ Xv,
                                                   const uint4* __restrict__ Wp,
                                                   const float* __restrict__ dinv,
                                                   unsigned short* __restrict__ Hb) {
    __shared__ float xs[64][C];        // 32 KB, reused as bf16 out-staging
    __shared__ float sd[64];
    const int t = threadIdx.x;
    const int r0 = blockIdx.x * 64;
    const bool full = (r0 + 64 <= N_NODES);

    if (BF16IN) {   // stage 64x128 bf16 tile (coalesced uint4)
        const uint4* X4 = (const uint4*)((const unsigned short*)Xv + (size_t)r0 * C);
        uint4* s4 = (uint4*)xs;        // first 16KB
        #pragma unroll
        for (int i = 0; i < 4; ++i) {
            int li = t + i * 256;      // 0..1023, row = li>>4
            if (full || (r0 + (li >> 4) < N_NODES)) s4[li] = X4[li];
            else s4[li] = make_uint4(0u, 0u, 0u, 0u);
        }
    } else {        // stage 64x128 fp32 tile (coalesced float4)
        const float4* X4 = (const float4*)((const float*)Xv + (size_t)r0 * C);
        float4* s4 = (float4*)xs;
        #pragma unroll
        for (int i = 0; i < 8; ++i) {
            int li = t + i * 256;
            if (full || (r0 + (li >> 5) < N_NODES)) s4[li] = X4[li];
            else s4[li] = make_float4(0.f, 0.f, 0.f, 0.f);
        }
    }
    if (t < 64) sd[t] = (r0 + t < N_NODES) ? dinv[r0 + t] : 1.f;
    __syncthreads();

    const int w = t >> 6;              // wave 0..3
    const int lane = t & 63;
    const int m = lane & 15;
    const int q = lane >> 4;
    const int arow = w * 16 + m;       // A row this lane reads

    f32x4 acc[8];
    #pragma unroll
    for (int i = 0; i < 8; ++i) acc[i] = (f32x4){0.f, 0.f, 0.f, 0.f};

    const bf16x8* Wp8 = (const bf16x8*)Wp;
    const unsigned short* xb = (const unsigned short*)xs;
    #pragma unroll
    for (int s = 0; s < 4; ++s) {
        const int k0 = s * 32 + q * 8;
        bf16x8 a;
        if (BF16IN) {
            a = *(const bf16x8*)&xb[arow * C + k0];
        } else {
            float4 va = *(const float4*)&xs[arow][k0];
            float4 vb = *(const float4*)&xs[arow][k0 + 4];
            a[0] = (short)f2bf(va.x); a[1] = (short)f2bf(va.y);
            a[2] = (short)f2bf(va.z); a[3] = (short)f2bf(va.w);
            a[4] = (short)f2bf(vb.x); a[5] = (short)f2bf(vb.y);
            a[6] = (short)f2bf(vb.z); a[7] = (short)f2bf(vb.w);
        }
        #pragma unroll
        for (int tt = 0; tt < 8; ++tt) {
            bf16x8 b = Wp8[(tt * 4 + s) * 64 + lane];
            acc[tt] = __builtin_amdgcn_mfma_f32_16x16x32_bf16(a, b, acc[tt], 0, 0, 0);
        }
    }

    __syncthreads();                   // all waves done reading xs
    unsigned short* hb = (unsigned short*)xs;   // 64x128 bf16 staging
    const int lrb = w * 16 + q * 4;
    #pragma unroll
    for (int r = 0; r < 4; ++r) {
        float sc = sd[lrb + r];
        #pragma unroll
        for (int tt = 0; tt < 8; ++tt)
            hb[(lrb + r) * C + tt * 16 + m] = f2bf(acc[tt][r] * sc);
    }
    __syncthreads();

    // coalesced store: 64x128 bf16 = 1024 uint4
    const uint4* src = (const uint4*)hb;
    uint4* dst = (uint4*)(Hb + (size_t)r0 * C);
    #pragma unroll
    for (int i = 0; i < 4; ++i) {
        int li = t + i * 256;
        if (full || (r0 + (li >> 4) < N_NODES)) dst[li] = src[li];
    }
}

// ---------------- layer-1 aggregation (round-8 form, unchanged) ----------------
#define ACC8(v)                                                             \
    do {                                                                    \
        f32x2 t0 = {__uint_as_float((v).x << 16),                           \
                    __uint_as_float((v).x & 0xffff0000u)};                  \
        f32x2 t1 = {__uint_as_float((v).y << 16),                           \
                    __uint_as_float((v).y & 0xffff0000u)};                  \
        f32x2 t2 = {__uint_as_float((v).z << 16),                           \
                    __uint_as_float((v).z & 0xffff0000u)};                  \
        f32x2 t3 = {__uint_as_float((v).w << 16),                           \
                    __uint_as_float((v).w & 0xffff0000u)};                  \
        acc2[0] += t0;                                                      \
        acc2[1] += t1;                                                      \
        acc2[2] += t2;                                                      \
        acc2[3] += t3;                                                      \
    } while (0)

// gather body shared by both aggregate kernels: accumulates into acc2[4]
#define GATHER_BODY(gid)                                                        \
    do {                                                                        \
        const int s0 = off[gid];                                                \
        const int e1 = off[(gid) + 1];                                          \
        const int deg = e1 - s0;                                                \
        {                                                                       \
            uint4 v = *(const uint4*)(Hbb + (((unsigned)(gid) << 8) + sl16));   \
            ACC8(v);                                                            \
        }                                                                       \
        int myidx = csr[min(s0 + sl, E_EDGES - 1)];                             \
        for (int base = 0; base < deg; base += 16) {                            \
            if (base) myidx = csr[min(s0 + base + sl, E_EDGES - 1)];            \
            for (int q = 0; q < 16 && base + q < deg; q += 4) {                 \
                const int p1 = base + q + 1, p2 = base + q + 2, p3 = base + q + 3; \
                int i0 = __shfl(myidx, grpbase + q + 0);                        \
                int i1 = (p1 < deg) ? __shfl(myidx, grpbase + q + 1) : ZROW;    \
                int i2 = (p2 < deg) ? __shfl(myidx, grpbase + q + 2) : ZROW;    \
                int i3 = (p3 < deg) ? __shfl(myidx, grpbase + q + 3) : ZROW;    \
                uint4 v0 = *(const uint4*)(Hbb + (((unsigned)i0 << 8) + sl16)); \
                uint4 v1 = *(const uint4*)(Hbb + (((unsigned)i1 << 8) + sl16)); \
                uint4 v2 = *(const uint4*)(Hbb + (((unsigned)i2 << 8) + sl16)); \
                uint4 v3 = *(const uint4*)(Hbb + (((unsigned)i3 << 8) + sl16)); \
                ACC8(v0);                                                       \
                ACC8(v1);                                                       \
                ACC8(v2);                                                       \
                ACC8(v3);                                                       \
            }                                                                   \
        }                                                                       \
    } while (0)

__global__ __launch_bounds__(256) void k_aggregate1(const uint4* __restrict__ Hb4,
                                                    const int* __restrict__ csr,
                                                    const int* __restrict__ off,
                                                    const float* __restrict__ dinv,
                                                    const float* __restrict__ bias,
                                                    unsigned short* __restrict__ Aout) {
    const int tid = threadIdx.x;
    const int gid = (blockIdx.x * 256 + tid) >> 4;   // node (16 lanes/node); grid exact
    if (gid >= N_NODES) return;                      // never taken (exact grid)
    const int sl = tid & 15;
    const int grpbase = (tid & 63) & 48;
    const unsigned sl16 = (unsigned)sl << 4;
    const char* Hbb = (const char*)Hb4;
    const float di = dinv[gid];

    f32x2 acc2[4];
    #pragma unroll
    for (int j = 0; j < 4; ++j) acc2[j] = (f32x2){0.f, 0.f};

    GATHER_BODY(gid);

    float4 b0 = ((const float4*)bias)[sl * 2];
    float4 b1 = ((const float4*)bias)[sl * 2 + 1];
    acc2[0] = acc2[0] * di + (f32x2){b0.x, b0.y};
    acc2[1] = acc2[1] * di + (f32x2){b0.z, b0.w};
    acc2[2] = acc2[2] * di + (f32x2){b1.x, b1.y};
    acc2[3] = acc2[3] * di + (f32x2){b1.z, b1.w};

    #pragma unroll
    for (int j = 0; j < 4; ++j) {
        acc2[j].x = fmaxf(acc2[j].x, 0.f);
        acc2[j].y = fmaxf(acc2[j].y, 0.f);
    }
    uint4 o;
    o.x = (unsigned)f2bf(acc2[0].x) | ((unsigned)f2bf(acc2[0].y) << 16);
    o.y = (unsigned)f2bf(acc2[1].x) | ((unsigned)f2bf(acc2[1].y) << 16);
    o.z = (unsigned)f2bf(acc2[2].x) | ((unsigned)f2bf(acc2[2].y) << 16);
    o.w = (unsigned)f2bf(acc2[3].x) | ((unsigned)f2bf(acc2[3].y) << 16);
    ((uint4*)Aout)[(size_t)gid * 16 + sl] = o;
}

// ---------------- layer-2 aggregation + normalize + FUSED MFMA DECODE ----------------
// BS=1024: 64 nodes/block. Gather+norm per 16-lane group (as k_aggregate1),
// emb -> out_emb fp32 AND bf16 row -> 16KB LDS. One barrier. Then the 4
// waves run k_decode_mfma's verified epilogue (4 col-tiles x 4 k-steps of
// 16x16x32 vs pre-packed Wd, row softmax over the 16-lane m-group).
// 16KB LDS @1024 thr = 1KB/wave (no occupancy hit); launch_bounds(,8) pins
// VGPR<=64 so gather wave-residency is protected (rounds 9-12 lesson).
__global__ __launch_bounds__(1024, 8) void k_agg_decode(const uint4* __restrict__ Hb4,
                                                        const int* __restrict__ csr,
                                                        const int* __restrict__ off,
                                                        const float* __restrict__ dinv,
                                                        const float* __restrict__ bias,
                                                        float* __restrict__ out_emb,
                                                        const uint4* __restrict__ Wpd,
                                                        const float* __restrict__ bd,
                                                        float* __restrict__ out_logp) {
    __shared__ unsigned short eb[64 * C];            // 16 KB bf16 emb tile
    const int tid = threadIdx.x;
    const int lrow = tid >> 4;                       // local node 0..63
    const int gid = blockIdx.x * 64 + lrow;
    const bool active = gid < N_NODES;               // tail: wave-uniform split
    const int sl = tid & 15;
    const int grpbase = (tid & 63) & 48;
    const unsigned sl16 = (unsigned)sl << 4;
    const char* Hbb = (const char*)Hb4;

    uint4 ebrow = make_uint4(0u, 0u, 0u, 0u);
    if (active) {
        const float di = dinv[gid];
        f32x2 acc2[4];
        #pragma unroll
        for (int j = 0; j < 4; ++j) acc2[j] = (f32x2){0.f, 0.f};

        GATHER_BODY(gid);

        float4 b0 = ((const float4*)bias)[sl * 2];
        float4 b1 = ((const float4*)bias)[sl * 2 + 1];
        acc2[0] = acc2[0] * di + (f32x2){b0.x, b0.y};
        acc2[1] = acc2[1] * di + (f32x2){b0.z, b0.w};
        acc2[2] = acc2[2] * di + (f32x2){b1.x, b1.y};
        acc2[3] = acc2[3] * di + (f32x2){b1.z, b1.w};

        float ss = 0.f;
        #pragma unroll
        for (int j = 0; j < 4; ++j) ss += acc2[j].x * acc2[j].x + acc2[j].y * acc2[j].y;
        #pragma unroll
        for (int o = 1; o < 16; o <<= 1) ss += __shfl_xor(ss, o);
        const float inv = 1.f / (sqrtf(ss) + 1e-12f);

        float hv[8] = {acc2[0].x * inv, acc2[0].y * inv, acc2[1].x * inv, acc2[1].y * inv,
                       acc2[2].x * inv, acc2[2].y * inv, acc2[3].x * inv, acc2[3].y * inv};

        // fp32 embedding out (required output)
        float4* dst = (float4*)(out_emb + (size_t)gid * C + sl * 8);
        dst[0] = make_float4(hv[0], hv[1], hv[2], hv[3]);
        dst[1] = make_float4(hv[4], hv[5], hv[6], hv[7]);

        // bf16 row chunk for the decode MFMA
        ebrow.x = (unsigned)f2bf(hv[0]) | ((unsigned)f2bf(hv[1]) << 16);
        ebrow.y = (unsigned)f2bf(hv[2]) | ((unsigned)f2bf(hv[3]) << 16);
        ebrow.z = (unsigned)f2bf(hv[4]) | ((unsigned)f2bf(hv[5]) << 16);
        ebrow.w = (unsigned)f2bf(hv[6]) | ((unsigned)f2bf(hv[7]) << 16);
    }
    ((uint4*)eb)[lrow * 16 + sl] = ebrow;            // zeros for inactive rows
    __syncthreads();

    // ---- MFMA decode epilogue (verbatim k_decode_mfma structure) ----
    const int w = tid >> 6 & 3;                      // wave-in-... 1024 thr = 16 waves
    // NOTE: 16 waves; waves 0..15. Map wave v (0..15) -> quarter v&3 of rows?
    // Simpler: only waves 0..3 (tid < 256) run the MFMA epilogue; the other
    // 12 waves exit. The epilogue is ~5% of kernel time; idle waves free
    // their slots for other blocks' gather waves.
    if (tid < 256) {
        const int lane = tid & 63;
        const int m = lane & 15;
        const int q = lane >> 4;
        const int wv = tid >> 6;                     // 0..3
        const int arow = wv * 16 + m;
        const int r0 = blockIdx.x * 64;

        f32x4 acc[4];
        #pragma unroll
        for (int i = 0; i < 4; ++i) acc[i] = (f32x4){0.f, 0.f, 0.f, 0.f};

        const bf16x8* Wp8 = (const bf16x8*)Wpd;
        #pragma unroll
        for (int s = 0; s < 4; ++s) {
            const int k0 = s * 32 + q * 8;
            bf16x8 a = *(const bf16x8*)&eb[arow * C + k0];
            #pragma unroll
            for (int tt = 0; tt < 4; ++tt) {
                bf16x8 b = Wp8[(tt * 4 + s) * 64 + lane];
                acc[tt] = __builtin_amdgcn_mfma_f32_16x16x32_bf16(a, b, acc[tt], 0, 0, 0);
            }
        }

        float bdv[4];
        #pragma unroll
        for (int tt = 0; tt < 4; ++tt) bdv[tt] = bd[tt * 16 + m];

        #pragma unroll
        for (int reg = 0; reg < 4; ++reg) {
            int row = r0 + wv * 16 + q * 4 + reg;
            float g0 = acc[0][reg] + bdv[0];
            float g1 = acc[1][reg] + bdv[1];
            float g2 = acc[2][reg] + bdv[2];
            float g3 = acc[3][reg] + bdv[3];
            float mx = fmaxf(fmaxf(g0, g1), fmaxf(g2, g3));
            #pragma unroll
            for (int o = 1; o < 16; o <<= 1) mx = fmaxf(mx, __shfl_xor(mx, o));
            float s = expf(g0 - mx) + expf(g1 - mx) + expf(g2 - mx) + expf(g3 - mx);
            #pragma unroll
            for (int o = 1; o < 16; o <<= 1) s += __shfl_xor(s, o);
            float ls = mx + logf(s);
            if (row < N_NODES) {
                float* op = &out_logp[(size_t)row * OUTC + m];
                op[0]  = g0 - ls;
                op[16] = g1 - ls;
                op[32] = g2 - ls;
                op[48] = g3 - ls;
            }
        }
    }
    (void)w;
}

extern "C" void kernel_launch(void* const* d_in, const int* in_sizes, int n_in,
                              void* d_out, int out_size, void* d_ws, size_t ws_size,
                              hipStream_t stream) {
    const float* x  = (const float*)d_in[0];
    const int*   ei = (const int*)d_in[1];
    const int* rowi = ei;
    const int* coli = ei + E_EDGES;
    const float* W1 = (const float*)d_in[2];
    const float* b1 = (const float*)d_in[3];
    const float* W2 = (const float*)d_in[4];
    const float* b2 = (const float*)d_in[5];
    const float* Wd = (const float*)d_in[6];
    const float* bd = (const float*)d_in[7];

    float* out_logp = (float*)d_out;                             // [N,64]
    float* out_emb  = (float*)d_out + (long long)N_NODES * OUTC; // [N,128]

    // workspace layout (16B-aligned regions)
    char* p = (char*)d_ws;
    float* dinv = (float*)p;                  p += sizeof(float) * N_NODES;
    unsigned short* Hb = (unsigned short*)p;  p += sizeof(short) * (size_t)(N_NODES + 4) * C; // +4 rows (ZROW pad)
    unsigned short* aggb = (unsigned short*)p; p += sizeof(short) * (size_t)N_NODES * C;      // bf16 h1
    int*   off   = (int*)p;                   p += sizeof(int) * (N_NODES + 4);
    int*   histG = (int*)p;                   p += sizeof(int) * SCM;
    int*   base  = (int*)p;                   p += sizeof(int) * SCM;
    int*   bsum  = (int*)p;                   p += sizeof(int) * 64;
    int*   tmp   = (int*)p;                   p += sizeof(int) * (size_t)E_EDGES;
    int*   csr   = (int*)p;                   p += sizeof(int) * (size_t)E_EDGES;
    uint4* Wp1   = (uint4*)p;                 p += sizeof(uint4) * 2048;
    uint4* Wp2   = (uint4*)p;                 p += sizeof(uint4) * 2048;
    uint4* Wpd   = (uint4*)p;                 p += sizeof(uint4) * 1024;

    // --- CSR front-end: 4 kernels (histogram+packs, scan, coarse, fine) ---
    k_histpack<<<CB_BLOCKS, CB_THREADS, 0, stream>>>(W1, Wp1, W2, Wp2, Wd, Wpd,
                                                     (uint4*)Hb, coli, histG);
    k_scanA<<<NSB, S1B, 0, stream>>>(histG, base, bsum);
    k_coarse<<<CB_BLOCKS, CB_THREADS, 0, stream>>>(rowi, coli, base, bsum, tmp);
    k_fine<<<NBKT, 256, 0, stream>>>(tmp, base, bsum, csr, off, dinv);

    const int GB = (N_NODES + 63) / 64;          // 1563
    const int AB = (N_NODES * 16 + 255) / 256;   // 6250 (16 lanes per node, exact)
    // --- conv1: H1b = (x@W1)*dinv -> gather-agg -> relu -> bf16 aggb ---
    k_gemm_mfma<false><<<GB, 256, 0, stream>>>(x, Wp1, dinv, Hb);
    k_aggregate1<<<AB, 256, 0, stream>>>((const uint4*)Hb, csr, off, dinv, b1, aggb);
    // --- conv2: H2b = (aggb@W2)*dinv -> gather-agg -> normalize -> out_emb
    //            + fused MFMA decode -> out_logp ---
    k_gemm_mfma<true><<<GB, 256, 0, stream>>>(aggb, Wp2, dinv, Hb);
    k_agg_decode<<<GB, 1024, 0, stream>>>((const uint4*)Hb, csr, off, dinv, b2, out_emb,
                                          Wpd, bd, out_logp);
}